// Round 1
// baseline (1419.475 us; speedup 1.0000x reference)
//
#include <hip/hip_runtime.h>
#include <hip/hip_bf16.h>
#include <math.h>

// Problem constants (match reference)
constexpr int B_   = 8;
constexpr int L_   = 1024;
constexpr int D_   = 512;
constexpr int DIN_ = 1024;   // EXPAND * D
constexpr int NST  = 16;     // DSTATE
constexpr int DTR  = 32;     // DTRANK
constexpr int BL_  = B_ * L_;
#define EPSV 1e-5f

__device__ __forceinline__ float sigmoidf_(float x) { return 1.f / (1.f + expf(-x)); }
__device__ __forceinline__ float softplusf_(float x) { return fmaxf(x, 0.f) + log1pf(expf(-fabsf(x))); }

// ---------------- LayerNorm over D_=512. block=256, 2 cols/thread. ----------------
// RES=true computes ln(x + res).
template <bool RES>
__global__ __launch_bounds__(256) void ln_k(const float* __restrict__ x,
                                            const float* __restrict__ res,
                                            const float* __restrict__ w,
                                            const float* __restrict__ b,
                                            float* __restrict__ out) {
  int row = blockIdx.x;
  int tid = threadIdx.x;
  const float* xr = x + (size_t)row * D_;
  float v0 = xr[tid], v1 = xr[tid + 256];
  if (RES) {
    const float* rr = res + (size_t)row * D_;
    v0 += rr[tid];
    v1 += rr[tid + 256];
  }
  float s = v0 + v1, ss = v0 * v0 + v1 * v1;
  __shared__ float r1[256], r2[256];
  r1[tid] = s; r2[tid] = ss;
  __syncthreads();
  for (int off = 128; off > 0; off >>= 1) {
    if (tid < off) { r1[tid] += r1[tid + off]; r2[tid] += r2[tid + off]; }
    __syncthreads();
  }
  float mean = r1[0] * (1.f / D_);
  float var  = r2[0] * (1.f / D_) - mean * mean;
  float rs   = rsqrtf(var + EPSV);
  float* orow = out + (size_t)row * D_;
  orow[tid]       = (v0 - mean) * rs * w[tid] + b[tid];
  orow[tid + 256] = (v1 - mean) * rs * w[tid + 256] + b[tid + 256];
}

// ---------------- Tiled f32 GEMM: C = A(MxK) @ B(KxN), optional bias+softplus ----------
// 64x64 tile, BK=16, 256 threads, 4x4 micro-tile. M,N %64==0, K %16==0 (all shapes here).
template <bool SP>
__global__ __launch_bounds__(256) void gemm_k(const float* __restrict__ A,
                                              const float* __restrict__ Bw,
                                              const float* __restrict__ bias,
                                              float* __restrict__ C,
                                              int M, int N, int K,
                                              int lda, int ldb, int ldc) {
  constexpr int BK = 16, LDP = 68;  // pad 64->68: float4-aligned, <=2-way bank alias
  __shared__ float As[BK * LDP];
  __shared__ float Bs[BK * LDP];
  int tid = threadIdx.x;
  int m0 = blockIdx.y * 64, n0 = blockIdx.x * 64;
  int tn = tid & 15, tm = tid >> 4;
  int am = tid >> 2, ak = (tid & 3) * 4;   // A tile: float4 along k
  int bn = tid & 63, bk = tid >> 6;        // B tile: 64-wide rows
  float acc[4][4] = {};
  for (int k0 = 0; k0 < K; k0 += BK) {
    float4 av = *(const float4*)(A + (size_t)(m0 + am) * lda + k0 + ak);
    As[(ak + 0) * LDP + am] = av.x;
    As[(ak + 1) * LDP + am] = av.y;
    As[(ak + 2) * LDP + am] = av.z;
    As[(ak + 3) * LDP + am] = av.w;
#pragma unroll
    for (int i = 0; i < 4; i++)
      Bs[(bk + 4 * i) * LDP + bn] = Bw[(size_t)(k0 + bk + 4 * i) * ldb + n0 + bn];
    __syncthreads();
#pragma unroll
    for (int kk = 0; kk < BK; kk++) {
      float4 a4 = *(const float4*)(As + kk * LDP + tm * 4);
      float4 b4 = *(const float4*)(Bs + kk * LDP + tn * 4);
      float a[4] = {a4.x, a4.y, a4.z, a4.w};
      float bb[4] = {b4.x, b4.y, b4.z, b4.w};
#pragma unroll
      for (int i = 0; i < 4; i++)
#pragma unroll
        for (int j = 0; j < 4; j++) acc[i][j] = fmaf(a[i], bb[j], acc[i][j]);
    }
    __syncthreads();
  }
#pragma unroll
  for (int i = 0; i < 4; i++) {
    float v[4];
#pragma unroll
    for (int j = 0; j < 4; j++) {
      float t = acc[i][j];
      if (SP) t = softplusf_(t + bias[n0 + tn * 4 + j]);
      v[j] = t;
    }
    float4 o = {v[0], v[1], v[2], v[3]};
    *(float4*)(C + (size_t)(m0 + tm * 4 + i) * ldc + n0 + tn * 4) = o;
  }
}

// ---------------- Causal depthwise conv (k=4) + bias + SiLU ----------------
// xp = xz[:, :, 0:DIN_]; out xc[b,t,d] = silu(sum_j xp[b,t-3+j,d]*cw[d,j] + cb[d])
__global__ __launch_bounds__(256) void conv_silu_k(const float* __restrict__ xz,
                                                   const float* __restrict__ cw,
                                                   const float* __restrict__ cb,
                                                   float* __restrict__ xc) {
  int idx = blockIdx.x * 256 + threadIdx.x;  // over BL_*DIN_
  int d  = idx & (DIN_ - 1);
  int bl = idx >> 10;
  int t  = bl & (L_ - 1);
  float acc = cb[d];
#pragma unroll
  for (int j = 0; j < 4; j++) {
    int tt = t - 3 + j;
    if (tt >= 0) acc = fmaf(xz[(size_t)(bl + tt - t) * (2 * DIN_) + d], cw[d * 4 + j], acc);
  }
  xc[idx] = acc * sigmoidf_(acc);
}

// ---------------- Selective scan ----------------
// block = 256 threads = 16 d-channels x 16 states. h in registers.
// Reads dt, xc (=silu'd conv out), dbl cols 32..47 (B) / 48..63 (C), z from xz.
// Writes y in place over xc (safe: each (b,t,d) read before written, disjoint across blocks).
__global__ __launch_bounds__(256) void scan_k(const float* __restrict__ dt,
                                              const float* __restrict__ dbl,
                                              const float* __restrict__ A_log,
                                              const float* __restrict__ Dskip,
                                              const float* __restrict__ xz,
                                              float* __restrict__ xc) {
  int n  = threadIdx.x & 15;
  int dl = threadIdx.x >> 4;
  int b  = blockIdx.x >> 6;   // 64 d-groups per batch
  int dg = blockIdx.x & 63;
  int d  = dg * 16 + dl;
  float Adn = -expf(A_log[d * NST + n]);
  float Dd  = Dskip[d];
  float h   = 0.f;
  size_t row0 = (size_t)b * L_;
  for (int t = 0; t < L_; ++t) {
    size_t r  = row0 + t;
    float dtv = dt[r * DIN_ + d];
    float xv  = xc[r * DIN_ + d];
    float Bn  = dbl[r * 64 + 32 + n];
    float Cn  = dbl[r * 64 + 48 + n];
    float dA  = expf(dtv * Adn);
    h = fmaf(dA, h, dtv * xv * Bn);
    float p = h * Cn;
    p += __shfl_xor(p, 8, 16);
    p += __shfl_xor(p, 4, 16);
    p += __shfl_xor(p, 2, 16);
    p += __shfl_xor(p, 1, 16);
    if (n == 0) {
      float z = xz[r * (2 * DIN_) + DIN_ + d];
      xc[r * DIN_ + d] = (p + xv * Dd) * (z * sigmoidf_(z));
    }
  }
}

extern "C" void kernel_launch(void* const* d_in, const int* in_sizes, int n_in,
                              void* d_out, int out_size, void* d_ws, size_t ws_size,
                              hipStream_t stream) {
  const float* x     = (const float*)d_in[0];
  const float* ln1w  = (const float*)d_in[1];
  const float* ln1b  = (const float*)d_in[2];
  const float* W_in  = (const float*)d_in[3];
  const float* convw = (const float*)d_in[4];
  const float* convb = (const float*)d_in[5];
  const float* W_x   = (const float*)d_in[6];
  const float* W_dt  = (const float*)d_in[7];
  const float* b_dt  = (const float*)d_in[8];
  const float* A_log = (const float*)d_in[9];
  const float* Dskip = (const float*)d_in[10];
  const float* W_out = (const float*)d_in[11];
  const float* ln2w  = (const float*)d_in[12];
  const float* ln2b  = (const float*)d_in[13];
  float* out = (float*)d_out;

  // Workspace layout (f32): total 38,273,024 floats = ~146 MiB
  float* ws  = (float*)d_ws;
  float* xn  = ws;                           // BL_*D_      (LN1 out; later reused as GEMM4 out)
  float* xz  = xn + (size_t)BL_ * D_;        // BL_*2*DIN_  (xp | z)
  float* xc  = xz + (size_t)BL_ * 2 * DIN_;  // BL_*DIN_    (conv out; later y in-place)
  float* dbl = xc + (size_t)BL_ * DIN_;      // BL_*64      (dt_r | B | C)
  float* dtb = dbl + (size_t)BL_ * 64;       // BL_*DIN_    (softplus dt)

  // 1. LN1
  ln_k<false><<<BL_, 256, 0, stream>>>(x, nullptr, ln1w, ln1b, xn);
  // 2. xz = xn @ W_in   (8192 x 2048 x 512)
  gemm_k<false><<<dim3((2 * DIN_) / 64, BL_ / 64), 256, 0, stream>>>(
      xn, W_in, nullptr, xz, BL_, 2 * DIN_, D_, D_, 2 * DIN_, 2 * DIN_);
  // 3. causal conv + silu
  conv_silu_k<<<(BL_ * DIN_) / 256, 256, 0, stream>>>(xz, convw, convb, xc);
  // 4. dbl = xc @ W_x   (8192 x 64 x 1024)
  gemm_k<false><<<dim3(1, BL_ / 64), 256, 0, stream>>>(
      xc, W_x, nullptr, dbl, BL_, 64, DIN_, DIN_, 64, 64);
  // 5. dt = softplus(dt_r @ W_dt + b_dt)   (8192 x 1024 x 32)
  gemm_k<true><<<dim3(DIN_ / 64, BL_ / 64), 256, 0, stream>>>(
      dbl, W_dt, b_dt, dtb, BL_, DIN_, DTR, 64, DIN_, DIN_);
  // 6. selective scan (+D skip, z gate), y overwrites xc
  scan_k<<<B_ * 64, 256, 0, stream>>>(dtb, dbl, A_log, Dskip, xz, xc);
  // 7. ymid = y @ W_out  (8192 x 512 x 1024), reuse xn
  gemm_k<false><<<dim3(D_ / 64, BL_ / 64), 256, 0, stream>>>(
      xc, W_out, nullptr, xn, BL_, D_, DIN_, DIN_, D_, D_);
  // 8. out = LN2(x + ymid)
  ln_k<true><<<BL_, 256, 0, stream>>>(x, xn, ln2w, ln2b, out);
}

// Round 2
// 885.742 us; speedup vs baseline: 1.6026x; 1.6026x over previous
//
#include <hip/hip_runtime.h>
#include <hip/hip_bf16.h>
#include <math.h>

// Problem constants (match reference)
constexpr int B_   = 8;
constexpr int L_   = 1024;
constexpr int D_   = 512;
constexpr int DIN_ = 1024;   // EXPAND * D
constexpr int NST  = 16;     // DSTATE
constexpr int DTR  = 32;     // DTRANK
constexpr int BL_  = B_ * L_;
constexpr int NC_  = 8;      // time chunks for parallel scan
constexpr int LC_  = L_ / NC_;  // 128 steps per chunk
#define EPSV 1e-5f

__device__ __forceinline__ float sigmoidf_(float x) { return 1.f / (1.f + expf(-x)); }
__device__ __forceinline__ float softplusf_(float x) { return fmaxf(x, 0.f) + log1pf(expf(-fabsf(x))); }

// ---------------- LayerNorm over D_=512. block=256, 2 cols/thread. ----------------
template <bool RES>
__global__ __launch_bounds__(256) void ln_k(const float* __restrict__ x,
                                            const float* __restrict__ res,
                                            const float* __restrict__ w,
                                            const float* __restrict__ b,
                                            float* __restrict__ out) {
  int row = blockIdx.x;
  int tid = threadIdx.x;
  const float* xr = x + (size_t)row * D_;
  float v0 = xr[tid], v1 = xr[tid + 256];
  if (RES) {
    const float* rr = res + (size_t)row * D_;
    v0 += rr[tid];
    v1 += rr[tid + 256];
  }
  float s = v0 + v1, ss = v0 * v0 + v1 * v1;
  __shared__ float r1[256], r2[256];
  r1[tid] = s; r2[tid] = ss;
  __syncthreads();
  for (int off = 128; off > 0; off >>= 1) {
    if (tid < off) { r1[tid] += r1[tid + off]; r2[tid] += r2[tid + off]; }
    __syncthreads();
  }
  float mean = r1[0] * (1.f / D_);
  float var  = r2[0] * (1.f / D_) - mean * mean;
  float rs   = rsqrtf(var + EPSV);
  float* orow = out + (size_t)row * D_;
  orow[tid]       = (v0 - mean) * rs * w[tid] + b[tid];
  orow[tid + 256] = (v1 - mean) * rs * w[tid + 256] + b[tid + 256];
}

// ---------------- Tiled f32 GEMM: C = A(MxK) @ B(KxN), optional bias+softplus ----------
template <bool SP>
__global__ __launch_bounds__(256) void gemm_k(const float* __restrict__ A,
                                              const float* __restrict__ Bw,
                                              const float* __restrict__ bias,
                                              float* __restrict__ C,
                                              int M, int N, int K,
                                              int lda, int ldb, int ldc) {
  constexpr int BK = 16, LDP = 68;
  __shared__ float As[BK * LDP];
  __shared__ float Bs[BK * LDP];
  int tid = threadIdx.x;
  int m0 = blockIdx.y * 64, n0 = blockIdx.x * 64;
  int tn = tid & 15, tm = tid >> 4;
  int am = tid >> 2, ak = (tid & 3) * 4;
  int bn = tid & 63, bk = tid >> 6;
  float acc[4][4] = {};
  for (int k0 = 0; k0 < K; k0 += BK) {
    float4 av = *(const float4*)(A + (size_t)(m0 + am) * lda + k0 + ak);
    As[(ak + 0) * LDP + am] = av.x;
    As[(ak + 1) * LDP + am] = av.y;
    As[(ak + 2) * LDP + am] = av.z;
    As[(ak + 3) * LDP + am] = av.w;
#pragma unroll
    for (int i = 0; i < 4; i++)
      Bs[(bk + 4 * i) * LDP + bn] = Bw[(size_t)(k0 + bk + 4 * i) * ldb + n0 + bn];
    __syncthreads();
#pragma unroll
    for (int kk = 0; kk < BK; kk++) {
      float4 a4 = *(const float4*)(As + kk * LDP + tm * 4);
      float4 b4 = *(const float4*)(Bs + kk * LDP + tn * 4);
      float a[4] = {a4.x, a4.y, a4.z, a4.w};
      float bb[4] = {b4.x, b4.y, b4.z, b4.w};
#pragma unroll
      for (int i = 0; i < 4; i++)
#pragma unroll
        for (int j = 0; j < 4; j++) acc[i][j] = fmaf(a[i], bb[j], acc[i][j]);
    }
    __syncthreads();
  }
#pragma unroll
  for (int i = 0; i < 4; i++) {
    float v[4];
#pragma unroll
    for (int j = 0; j < 4; j++) {
      float t = acc[i][j];
      if (SP) t = softplusf_(t + bias[n0 + tn * 4 + j]);
      v[j] = t;
    }
    float4 o = {v[0], v[1], v[2], v[3]};
    *(float4*)(C + (size_t)(m0 + tm * 4 + i) * ldc + n0 + tn * 4) = o;
  }
}

// ---------------- Causal depthwise conv (k=4) + bias + SiLU ----------------
__global__ __launch_bounds__(256) void conv_silu_k(const float* __restrict__ xz,
                                                   const float* __restrict__ cw,
                                                   const float* __restrict__ cb,
                                                   float* __restrict__ xc) {
  int idx = blockIdx.x * 256 + threadIdx.x;  // over BL_*DIN_
  int d  = idx & (DIN_ - 1);
  int bl = idx >> 10;
  int t  = bl & (L_ - 1);
  float acc = cb[d];
#pragma unroll
  for (int j = 0; j < 4; j++) {
    int tt = t - 3 + j;
    if (tt >= 0) acc = fmaf(xz[(size_t)(bl + tt - t) * (2 * DIN_) + d], cw[d * 4 + j], acc);
  }
  xc[idx] = acc * sigmoidf_(acc);
}

// ---------------- Chunked selective scan ----------------
// Pass 1: per-chunk summaries. h_end = P*h_start + S with P = prod(dA), S = local scan.
// block = 256 thr = 16 d x 16 n; grid = B * 64 dgroups * NC chunks. Loads prefetched by 1.
__global__ __launch_bounds__(256) void scan1_k(const float* __restrict__ dt,
                                               const float* __restrict__ dbl,
                                               const float* __restrict__ A_log,
                                               const float* __restrict__ xc,
                                               float* __restrict__ Pb,
                                               float* __restrict__ Sb) {
  int n  = threadIdx.x & 15;
  int dl = threadIdx.x >> 4;
  int dg = blockIdx.x & 63;
  int c  = (blockIdx.x >> 6) & (NC_ - 1);
  int b  = blockIdx.x >> 9;   // / (64*NC_)
  int d  = dg * 16 + dl;
  float Adn = -expf(A_log[d * NST + n]);
  float P = 1.f, S = 0.f;
  size_t row0 = (size_t)b * L_ + (size_t)c * LC_;
  // prefetch t=0
  float dtv = dt[row0 * DIN_ + d];
  float xv  = xc[row0 * DIN_ + d];
  float Bn  = dbl[row0 * 64 + 32 + n];
  for (int t = 0; t < LC_; ++t) {
    size_t rn = row0 + (t + 1 < LC_ ? t + 1 : t);  // clamp: last iter reloads (discarded)
    float dtv2 = dt[rn * DIN_ + d];
    float xv2  = xc[rn * DIN_ + d];
    float Bn2  = dbl[rn * 64 + 32 + n];
    float dA = expf(dtv * Adn);
    S = fmaf(dA, S, dtv * xv * Bn);
    P *= dA;
    dtv = dtv2; xv = xv2; Bn = Bn2;
  }
  size_t idx = ((size_t)(b * NC_ + c) * DIN_ + d) * NST + n;
  Pb[idx] = P;
  Sb[idx] = S;
}

// Pass 2: sequential combine over NC_ chunks -> per-chunk initial state h0.
__global__ __launch_bounds__(256) void comb_k(const float* __restrict__ Pb,
                                              const float* __restrict__ Sb,
                                              float* __restrict__ h0) {
  int gid = blockIdx.x * 256 + threadIdx.x;       // over B_*DIN_*NST
  int b   = gid >> 14;                            // / (DIN_*NST)
  int rem = gid & (DIN_ * NST - 1);
  float h = 0.f;
#pragma unroll
  for (int c = 0; c < NC_; ++c) {
    size_t idx = (size_t)(b * NC_ + c) * DIN_ * NST + rem;
    h0[idx] = h;
    h = fmaf(Pb[idx], h, Sb[idx]);
  }
}

// Pass 3: re-run each chunk from h0, emit y (+D skip, z gate) in place over xc.
// Prefetch loads issued BEFORE the store each iteration -> no alias stall.
__global__ __launch_bounds__(256) void scan3_k(const float* __restrict__ dt,
                                               const float* __restrict__ dbl,
                                               const float* __restrict__ A_log,
                                               const float* __restrict__ Dskip,
                                               const float* __restrict__ xz,
                                               const float* __restrict__ h0,
                                               float* __restrict__ xc) {
  int n  = threadIdx.x & 15;
  int dl = threadIdx.x >> 4;
  int dg = blockIdx.x & 63;
  int c  = (blockIdx.x >> 6) & (NC_ - 1);
  int b  = blockIdx.x >> 9;
  int d  = dg * 16 + dl;
  float Adn = -expf(A_log[d * NST + n]);
  float Dd  = Dskip[d];
  size_t sidx = ((size_t)(b * NC_ + c) * DIN_ + d) * NST + n;
  float h = h0[sidx];
  size_t row0 = (size_t)b * L_ + (size_t)c * LC_;
  float dtv = dt[row0 * DIN_ + d];
  float xv  = xc[row0 * DIN_ + d];
  float Bn  = dbl[row0 * 64 + 32 + n];
  float Cn  = dbl[row0 * 64 + 48 + n];
  float zv  = xz[row0 * (2 * DIN_) + DIN_ + d];
  for (int t = 0; t < LC_; ++t) {
    size_t r  = row0 + t;
    size_t rn = row0 + (t + 1 < LC_ ? t + 1 : t);
    float dtv2 = dt[rn * DIN_ + d];
    float xv2  = xc[rn * DIN_ + d];
    float Bn2  = dbl[rn * 64 + 32 + n];
    float Cn2  = dbl[rn * 64 + 48 + n];
    float zv2  = xz[rn * (2 * DIN_) + DIN_ + d];
    float dA = expf(dtv * Adn);
    h = fmaf(dA, h, dtv * xv * Bn);
    float p = h * Cn;
    p += __shfl_xor(p, 8, 16);
    p += __shfl_xor(p, 4, 16);
    p += __shfl_xor(p, 2, 16);
    p += __shfl_xor(p, 1, 16);
    if (n == 0)
      xc[r * DIN_ + d] = (p + xv * Dd) * (zv * sigmoidf_(zv));
    dtv = dtv2; xv = xv2; Bn = Bn2; Cn = Cn2; zv = zv2;
  }
}

extern "C" void kernel_launch(void* const* d_in, const int* in_sizes, int n_in,
                              void* d_out, int out_size, void* d_ws, size_t ws_size,
                              hipStream_t stream) {
  const float* x     = (const float*)d_in[0];
  const float* ln1w  = (const float*)d_in[1];
  const float* ln1b  = (const float*)d_in[2];
  const float* W_in  = (const float*)d_in[3];
  const float* convw = (const float*)d_in[4];
  const float* convb = (const float*)d_in[5];
  const float* W_x   = (const float*)d_in[6];
  const float* W_dt  = (const float*)d_in[7];
  const float* b_dt  = (const float*)d_in[8];
  const float* A_log = (const float*)d_in[9];
  const float* Dskip = (const float*)d_in[10];
  const float* W_out = (const float*)d_in[11];
  const float* ln2w  = (const float*)d_in[12];
  const float* ln2b  = (const float*)d_in[13];
  float* out = (float*)d_out;

  // Workspace layout (f32), same footprint as round 0 (~146 MiB):
  float* ws  = (float*)d_ws;
  float* xn  = ws;                           // BL_*D_ (LN1 out; dead between GEMM2 and GEMM7)
  float* xz  = xn + (size_t)BL_ * D_;        // BL_*2*DIN_  (xp | z)
  float* xc  = xz + (size_t)BL_ * 2 * DIN_;  // BL_*DIN_    (conv out; y in-place)
  float* dbl = xc + (size_t)BL_ * DIN_;      // BL_*64      (dt_r | B | C)
  float* dtb = dbl + (size_t)BL_ * 64;       // BL_*DIN_    (softplus dt)
  // P/S/h0 overlay the dead xn region: 3 * B_*NC_*DIN_*NST = 3M floats <= BL_*D_ = 4M floats.
  constexpr size_t PSZ = (size_t)B_ * NC_ * DIN_ * NST;  // 1,048,576
  float* Pb = xn;
  float* Sb = xn + PSZ;
  float* h0 = xn + 2 * PSZ;

  // 1. LN1
  ln_k<false><<<BL_, 256, 0, stream>>>(x, nullptr, ln1w, ln1b, xn);
  // 2. xz = xn @ W_in   (8192 x 2048 x 512)
  gemm_k<false><<<dim3((2 * DIN_) / 64, BL_ / 64), 256, 0, stream>>>(
      xn, W_in, nullptr, xz, BL_, 2 * DIN_, D_, D_, 2 * DIN_, 2 * DIN_);
  // 3. causal conv + silu
  conv_silu_k<<<(BL_ * DIN_) / 256, 256, 0, stream>>>(xz, convw, convb, xc);
  // 4. dbl = xc @ W_x   (8192 x 64 x 1024)
  gemm_k<false><<<dim3(1, BL_ / 64), 256, 0, stream>>>(
      xc, W_x, nullptr, dbl, BL_, 64, DIN_, DIN_, 64, 64);
  // 5. dt = softplus(dt_r @ W_dt + b_dt)   (8192 x 1024 x 32)
  gemm_k<true><<<dim3(DIN_ / 64, BL_ / 64), 256, 0, stream>>>(
      dbl, W_dt, b_dt, dtb, BL_, DIN_, DTR, 64, DIN_, DIN_);
  // 6. chunked selective scan (NOTE: P/S/h0 overlay xn — xn is dead here)
  scan1_k<<<B_ * 64 * NC_, 256, 0, stream>>>(dtb, dbl, A_log, xc, Pb, Sb);
  comb_k<<<(B_ * DIN_ * NST) / 256, 256, 0, stream>>>(Pb, Sb, h0);
  scan3_k<<<B_ * 64 * NC_, 256, 0, stream>>>(dtb, dbl, A_log, Dskip, xz, h0, xc);
  // 7. ymid = y @ W_out  (8192 x 512 x 1024), reuse xn (P/S/h0 dead now)
  gemm_k<false><<<dim3(D_ / 64, BL_ / 64), 256, 0, stream>>>(
      xc, W_out, nullptr, xn, BL_, D_, DIN_, DIN_, D_, D_);
  // 8. out = LN2(x + ymid)
  ln_k<true><<<BL_, 256, 0, stream>>>(x, xn, ln2w, ln2b, out);
}

// Round 3
// 549.588 us; speedup vs baseline: 2.5828x; 1.6116x over previous
//
#include <hip/hip_runtime.h>
#include <hip/hip_bf16.h>
#include <math.h>

// Problem constants (match reference)
constexpr int B_   = 8;
constexpr int L_   = 1024;
constexpr int D_   = 512;
constexpr int DIN_ = 1024;   // EXPAND * D
constexpr int NST  = 16;     // DSTATE
constexpr int DTR  = 32;     // DTRANK
constexpr int BL_  = B_ * L_;
constexpr int NC_  = 8;      // time chunks for parallel scan
constexpr int LC_  = L_ / NC_;  // 128 steps per chunk
#define EPSV 1e-5f

typedef __attribute__((ext_vector_type(8))) short short8;   // 8 bf16 = 4 VGPRs (MFMA A/B frag)
typedef __attribute__((ext_vector_type(4))) float f32x4;    // MFMA C/D frag

__device__ __forceinline__ float sigmoidf_(float x) { return 1.f / (1.f + expf(-x)); }
__device__ __forceinline__ float softplusf_(float x) { return fmaxf(x, 0.f) + log1pf(expf(-fabsf(x))); }

// async global->LDS, 16B per lane. LDS dest = wave-uniform base + lane*16.
__device__ __forceinline__ void gld16(const void* g, void* l) {
  __builtin_amdgcn_global_load_lds((const __attribute__((address_space(1))) void*)g,
                                   (__attribute__((address_space(3))) void*)l, 16, 0, 0);
}

// ---------------- LayerNorm over D_=512. block=256, 2 cols/thread. TO = float or bf16 out. ----
template <bool RES, typename TO>
__global__ __launch_bounds__(256) void ln_k(const float* __restrict__ x,
                                            const float* __restrict__ res,
                                            const float* __restrict__ w,
                                            const float* __restrict__ b,
                                            TO* __restrict__ out) {
  int row = blockIdx.x;
  int tid = threadIdx.x;
  const float* xr = x + (size_t)row * D_;
  float v0 = xr[tid], v1 = xr[tid + 256];
  if (RES) {
    const float* rr = res + (size_t)row * D_;
    v0 += rr[tid];
    v1 += rr[tid + 256];
  }
  float s = v0 + v1, ss = v0 * v0 + v1 * v1;
  __shared__ float r1[256], r2[256];
  r1[tid] = s; r2[tid] = ss;
  __syncthreads();
  for (int off = 128; off > 0; off >>= 1) {
    if (tid < off) { r1[tid] += r1[tid + off]; r2[tid] += r2[tid + off]; }
    __syncthreads();
  }
  float mean = r1[0] * (1.f / D_);
  float var  = r2[0] * (1.f / D_) - mean * mean;
  float rs   = rsqrtf(var + EPSV);
  float o0 = (v0 - mean) * rs * w[tid] + b[tid];
  float o1 = (v1 - mean) * rs * w[tid + 256] + b[tid + 256];
  TO* orow = out + (size_t)row * D_;
  if constexpr (sizeof(TO) == 2) {
    orow[tid]       = __float2bfloat16(o0);
    orow[tid + 256] = __float2bfloat16(o1);
  } else {
    orow[tid]       = o0;
    orow[tid + 256] = o1;
  }
}

// ---------------- transpose-cast: W (K x N, f32) -> Wt (N x K, bf16) ----------------
__global__ __launch_bounds__(256) void transpose_cast_k(const float* __restrict__ W,
                                                        __hip_bfloat16* __restrict__ Wt,
                                                        int K, int N) {
  __shared__ float t[32][33];
  int c = threadIdx.x & 31, r8 = threadIdx.x >> 5;  // 8 rows per pass
  int n0 = blockIdx.x * 32, k0 = blockIdx.y * 32;
#pragma unroll
  for (int rr = 0; rr < 4; rr++) {
    int k = k0 + r8 + rr * 8;
    t[r8 + rr * 8][c] = W[(size_t)k * N + n0 + c];
  }
  __syncthreads();
#pragma unroll
  for (int rr = 0; rr < 4; rr++) {
    int n = n0 + r8 + rr * 8;
    Wt[(size_t)n * K + k0 + c] = __float2bfloat16(t[c][r8 + rr * 8]);
  }
}

// ---------------- zero f32 buffer (avoid memset-in-capture doubt) ----------------
__global__ __launch_bounds__(256) void zero_k(float4* __restrict__ p) {
  p[(size_t)blockIdx.x * 256 + threadIdx.x] = float4{0.f, 0.f, 0.f, 0.f};
}

// ---------------- bf16 MFMA GEMM: C(f32 MxN) = A(bf16 MxK) @ Bt(bf16 NxK)^T ------------
// 128x128 tile, BK=32, 256 thr = 4 waves (2x2 of 64x64). m97 structure:
// global_load_lds(16B) staging -> barrier -> 8 ds_read_b128 + 16 MFMA -> barrier.
// M%128==0, N%128==0, K%32==0.
__global__ __launch_bounds__(256) void gemm_mfma_k(const __hip_bfloat16* __restrict__ A,
                                                   const __hip_bfloat16* __restrict__ Bt,
                                                   float* __restrict__ C,
                                                   int M, int N, int K) {
  __shared__ __align__(16) __hip_bfloat16 As[128 * 32];
  __shared__ __align__(16) __hip_bfloat16 Bs[128 * 32];
  int tid = threadIdx.x, w = tid >> 6, l = tid & 63;
  int m0 = blockIdx.y * 128, n0 = blockIdx.x * 128;
  int wm = (w >> 1) * 64, wn = (w & 1) * 64;
  int m16 = l & 15, q = l >> 4;
  int lr = l >> 2, lc = (l & 3) * 8;  // staging: row-in-16, elem chunk
  f32x4 acc[4][4] = {};
  for (int k0 = 0; k0 < K; k0 += 32) {
#pragma unroll
    for (int p = 0; p < 2; p++) {
      int rg = p * 4 + w;  // row-group of 16 (0..7)
      gld16(A  + (size_t)(m0 + rg * 16 + lr) * K + k0 + lc, As + rg * 512);
      gld16(Bt + (size_t)(n0 + rg * 16 + lr) * K + k0 + lc, Bs + rg * 512);
    }
    __syncthreads();
    short8 av[4], bv[4];
#pragma unroll
    for (int i = 0; i < 4; i++)
      av[i] = *(const short8*)(As + (wm + i * 16 + m16) * 32 + q * 8);
#pragma unroll
    for (int j = 0; j < 4; j++)
      bv[j] = *(const short8*)(Bs + (wn + j * 16 + m16) * 32 + q * 8);
#pragma unroll
    for (int i = 0; i < 4; i++)
#pragma unroll
      for (int j = 0; j < 4; j++)
        acc[i][j] = __builtin_amdgcn_mfma_f32_16x16x32_bf16(av[i], bv[j], acc[i][j], 0, 0, 0);
    __syncthreads();
  }
  // C/D layout: col = lane&15, row = (lane>>4)*4 + r  [m89/m91 verified]
#pragma unroll
  for (int i = 0; i < 4; i++)
#pragma unroll
    for (int j = 0; j < 4; j++)
#pragma unroll
      for (int r = 0; r < 4; r++) {
        int gm = m0 + wm + i * 16 + q * 4 + r;
        int gn = n0 + wn + j * 16 + m16;
        C[(size_t)gm * N + gn] = acc[i][j][r];
      }
}

// ---- N=64 variant with split-K (for xp @ W_x): tile 128x64, grid=(SK, M/128), atomicAdd.
__global__ __launch_bounds__(256) void gemm_mfma_n64_k(const __hip_bfloat16* __restrict__ A,
                                                       const __hip_bfloat16* __restrict__ Bt,
                                                       float* __restrict__ C,
                                                       int M, int K) {
  __shared__ __align__(16) __hip_bfloat16 As[128 * 32];
  __shared__ __align__(16) __hip_bfloat16 Bs[64 * 32];
  int tid = threadIdx.x, w = tid >> 6, l = tid & 63;
  int m0 = blockIdx.y * 128;
  int kper = K / gridDim.x, kbeg = blockIdx.x * kper;
  int m16 = l & 15, q = l >> 4;
  int lr = l >> 2, lc = (l & 3) * 8;
  f32x4 acc[2][4] = {};
  for (int k0 = kbeg; k0 < kbeg + kper; k0 += 32) {
#pragma unroll
    for (int p = 0; p < 2; p++) {
      int rg = p * 4 + w;
      gld16(A + (size_t)(m0 + rg * 16 + lr) * K + k0 + lc, As + rg * 512);
    }
    gld16(Bt + (size_t)(w * 16 + lr) * K + k0 + lc, Bs + w * 512);
    __syncthreads();
    short8 av[2], bv[4];
#pragma unroll
    for (int i = 0; i < 2; i++)
      av[i] = *(const short8*)(As + (w * 32 + i * 16 + m16) * 32 + q * 8);
#pragma unroll
    for (int j = 0; j < 4; j++)
      bv[j] = *(const short8*)(Bs + (j * 16 + m16) * 32 + q * 8);
#pragma unroll
    for (int i = 0; i < 2; i++)
#pragma unroll
      for (int j = 0; j < 4; j++)
        acc[i][j] = __builtin_amdgcn_mfma_f32_16x16x32_bf16(av[i], bv[j], acc[i][j], 0, 0, 0);
    __syncthreads();
  }
#pragma unroll
  for (int i = 0; i < 2; i++)
#pragma unroll
    for (int j = 0; j < 4; j++)
#pragma unroll
      for (int r = 0; r < 4; r++) {
        int gm = m0 + w * 32 + i * 16 + q * 4 + r;
        int gn = j * 16 + m16;
        atomicAdd(&C[(size_t)gm * 64 + gn], acc[i][j][r]);
      }
}

// ---------------- Tiled f32 GEMM (kept for the tiny K=32 dt GEMM) ----------------
template <bool SP>
__global__ __launch_bounds__(256) void gemm_k(const float* __restrict__ A,
                                              const float* __restrict__ Bw,
                                              const float* __restrict__ bias,
                                              float* __restrict__ C,
                                              int M, int N, int K,
                                              int lda, int ldb, int ldc) {
  constexpr int BK = 16, LDP = 68;
  __shared__ float As[BK * LDP];
  __shared__ float Bs[BK * LDP];
  int tid = threadIdx.x;
  int m0 = blockIdx.y * 64, n0 = blockIdx.x * 64;
  int tn = tid & 15, tm = tid >> 4;
  int am = tid >> 2, ak = (tid & 3) * 4;
  int bn = tid & 63, bk = tid >> 6;
  float acc[4][4] = {};
  for (int k0 = 0; k0 < K; k0 += BK) {
    float4 av = *(const float4*)(A + (size_t)(m0 + am) * lda + k0 + ak);
    As[(ak + 0) * LDP + am] = av.x;
    As[(ak + 1) * LDP + am] = av.y;
    As[(ak + 2) * LDP + am] = av.z;
    As[(ak + 3) * LDP + am] = av.w;
#pragma unroll
    for (int i = 0; i < 4; i++)
      Bs[(bk + 4 * i) * LDP + bn] = Bw[(size_t)(k0 + bk + 4 * i) * ldb + n0 + bn];
    __syncthreads();
#pragma unroll
    for (int kk = 0; kk < BK; kk++) {
      float4 a4 = *(const float4*)(As + kk * LDP + tm * 4);
      float4 b4 = *(const float4*)(Bs + kk * LDP + tn * 4);
      float a[4] = {a4.x, a4.y, a4.z, a4.w};
      float bb[4] = {b4.x, b4.y, b4.z, b4.w};
#pragma unroll
      for (int i = 0; i < 4; i++)
#pragma unroll
        for (int j = 0; j < 4; j++) acc[i][j] = fmaf(a[i], bb[j], acc[i][j]);
    }
    __syncthreads();
  }
#pragma unroll
  for (int i = 0; i < 4; i++) {
    float v[4];
#pragma unroll
    for (int j = 0; j < 4; j++) {
      float t = acc[i][j];
      if (SP) t = softplusf_(t + bias[n0 + tn * 4 + j]);
      v[j] = t;
    }
    float4 o = {v[0], v[1], v[2], v[3]};
    *(float4*)(C + (size_t)(m0 + tm * 4 + i) * ldc + n0 + tn * 4) = o;
  }
}

// ---------------- Causal depthwise conv (k=4) + bias + SiLU -> bf16 ----------------
__global__ __launch_bounds__(256) void conv_silu_k(const float* __restrict__ xz,
                                                   const float* __restrict__ cw,
                                                   const float* __restrict__ cb,
                                                   __hip_bfloat16* __restrict__ xcb) {
  int idx = blockIdx.x * 256 + threadIdx.x;  // over BL_*DIN_
  int d  = idx & (DIN_ - 1);
  int bl = idx >> 10;
  int t  = bl & (L_ - 1);
  float acc = cb[d];
#pragma unroll
  for (int j = 0; j < 4; j++) {
    int tt = t - 3 + j;
    if (tt >= 0) acc = fmaf(xz[(size_t)(bl + tt - t) * (2 * DIN_) + d], cw[d * 4 + j], acc);
  }
  xcb[idx] = __float2bfloat16(acc * sigmoidf_(acc));
}

// ---------------- Chunked selective scan (xv read as bf16) ----------------
__global__ __launch_bounds__(256) void scan1_k(const float* __restrict__ dt,
                                               const float* __restrict__ dbl,
                                               const float* __restrict__ A_log,
                                               const __hip_bfloat16* __restrict__ xcb,
                                               float* __restrict__ Pb,
                                               float* __restrict__ Sb) {
  int n  = threadIdx.x & 15;
  int dl = threadIdx.x >> 4;
  int dg = blockIdx.x & 63;
  int c  = (blockIdx.x >> 6) & (NC_ - 1);
  int b  = blockIdx.x >> 9;
  int d  = dg * 16 + dl;
  float Adn = -expf(A_log[d * NST + n]);
  float P = 1.f, S = 0.f;
  size_t row0 = (size_t)b * L_ + (size_t)c * LC_;
  float dtv = dt[row0 * DIN_ + d];
  float xv  = __bfloat162float(xcb[row0 * DIN_ + d]);
  float Bn  = dbl[row0 * 64 + 32 + n];
  for (int t = 0; t < LC_; ++t) {
    size_t rn = row0 + (t + 1 < LC_ ? t + 1 : t);
    float dtv2 = dt[rn * DIN_ + d];
    float xv2  = __bfloat162float(xcb[rn * DIN_ + d]);
    float Bn2  = dbl[rn * 64 + 32 + n];
    float dA = expf(dtv * Adn);
    S = fmaf(dA, S, dtv * xv * Bn);
    P *= dA;
    dtv = dtv2; xv = xv2; Bn = Bn2;
  }
  size_t idx = ((size_t)(b * NC_ + c) * DIN_ + d) * NST + n;
  Pb[idx] = P;
  Sb[idx] = S;
}

__global__ __launch_bounds__(256) void comb_k(const float* __restrict__ Pb,
                                              const float* __restrict__ Sb,
                                              float* __restrict__ h0) {
  int gid = blockIdx.x * 256 + threadIdx.x;  // over B_*DIN_*NST
  int b   = gid >> 14;
  int rem = gid & (DIN_ * NST - 1);
  float h = 0.f;
#pragma unroll
  for (int c = 0; c < NC_; ++c) {
    size_t idx = (size_t)(b * NC_ + c) * DIN_ * NST + rem;
    h0[idx] = h;
    h = fmaf(Pb[idx], h, Sb[idx]);
  }
}

// Pass 3: re-run chunk from h0, emit gated y as bf16 IN PLACE over xcb.
// Safe: reads of row r+1 precede the (lane n==0) store to row r; rows strictly increase.
__global__ __launch_bounds__(256) void scan3_k(const float* __restrict__ dt,
                                               const float* __restrict__ dbl,
                                               const float* __restrict__ A_log,
                                               const float* __restrict__ Dskip,
                                               const float* __restrict__ xz,
                                               const float* __restrict__ h0,
                                               __hip_bfloat16* __restrict__ xcb) {
  int n  = threadIdx.x & 15;
  int dl = threadIdx.x >> 4;
  int dg = blockIdx.x & 63;
  int c  = (blockIdx.x >> 6) & (NC_ - 1);
  int b  = blockIdx.x >> 9;
  int d  = dg * 16 + dl;
  float Adn = -expf(A_log[d * NST + n]);
  float Dd  = Dskip[d];
  size_t sidx = ((size_t)(b * NC_ + c) * DIN_ + d) * NST + n;
  float h = h0[sidx];
  size_t row0 = (size_t)b * L_ + (size_t)c * LC_;
  float dtv = dt[row0 * DIN_ + d];
  float xv  = __bfloat162float(xcb[row0 * DIN_ + d]);
  float Bn  = dbl[row0 * 64 + 32 + n];
  float Cn  = dbl[row0 * 64 + 48 + n];
  float zv  = xz[row0 * (2 * DIN_) + DIN_ + d];
  for (int t = 0; t < LC_; ++t) {
    size_t r  = row0 + t;
    size_t rn = row0 + (t + 1 < LC_ ? t + 1 : t);
    float dtv2 = dt[rn * DIN_ + d];
    float xv2  = __bfloat162float(xcb[rn * DIN_ + d]);
    float Bn2  = dbl[rn * 64 + 32 + n];
    float Cn2  = dbl[rn * 64 + 48 + n];
    float zv2  = xz[rn * (2 * DIN_) + DIN_ + d];
    float dA = expf(dtv * Adn);
    h = fmaf(dA, h, dtv * xv * Bn);
    float p = h * Cn;
    p += __shfl_xor(p, 8, 16);
    p += __shfl_xor(p, 4, 16);
    p += __shfl_xor(p, 2, 16);
    p += __shfl_xor(p, 1, 16);
    if (n == 0)
      xcb[r * DIN_ + d] = __float2bfloat16((p + xv * Dd) * (zv * sigmoidf_(zv)));
    dtv = dtv2; xv = xv2; Bn = Bn2; Cn = Cn2; zv = zv2;
  }
}

extern "C" void kernel_launch(void* const* d_in, const int* in_sizes, int n_in,
                              void* d_out, int out_size, void* d_ws, size_t ws_size,
                              hipStream_t stream) {
  const float* x     = (const float*)d_in[0];
  const float* ln1w  = (const float*)d_in[1];
  const float* ln1b  = (const float*)d_in[2];
  const float* W_in  = (const float*)d_in[3];
  const float* convw = (const float*)d_in[4];
  const float* convb = (const float*)d_in[5];
  const float* W_x   = (const float*)d_in[6];
  const float* W_dt  = (const float*)d_in[7];
  const float* b_dt  = (const float*)d_in[8];
  const float* A_log = (const float*)d_in[9];
  const float* Dskip = (const float*)d_in[10];
  const float* W_out = (const float*)d_in[11];
  const float* ln2w  = (const float*)d_in[12];
  const float* ln2b  = (const float*)d_in[13];
  float* out = (float*)d_out;

  // Workspace layout (~133 MiB total, under the proven 146 MiB):
  float* ws  = (float*)d_ws;
  float* xz  = ws;                            // BL*2048 f32 (xp | z)              64 MB
  float* dtb = xz + (size_t)BL_ * 2 * DIN_;   // BL*1024 f32 (softplus dt)         32 MB
  float* dbl = dtb + (size_t)BL_ * DIN_;      // BL*64  f32 (dt_r | B | C)          2 MB
  float* r0  = dbl + (size_t)BL_ * 64;        // 4M f32 region, time-multiplexed:  16 MB
  //   r0 as bf16 xnb  [LN1 -> GEMM1],  as P/S/h0 [scan1 -> scan3],  as f32 ymid [GEMM7 -> LN2]
  __hip_bfloat16* xnb = (__hip_bfloat16*)r0;            // BL*512 bf16 (8 MB of r0)
  constexpr size_t PSZ = (size_t)B_ * NC_ * DIN_ * NST; // 1M floats
  float* Pb = r0;
  float* Sb = r0 + PSZ;
  float* h0 = r0 + 2 * PSZ;
  float* ymid = r0;                                     // BL*512 f32
  __hip_bfloat16* xcb = (__hip_bfloat16*)(r0 + (size_t)BL_ * D_);  // BL*1024 bf16: conv out, then y in-place  16 MB
  __hip_bfloat16* wt_in  = xcb + (size_t)BL_ * DIN_;    // 2048x512 bf16 (W_in^T)
  __hip_bfloat16* wt_x   = wt_in + 2048 * 512;          // 64x1024 bf16 (W_x^T)
  __hip_bfloat16* wt_out = wt_x + 64 * 1024;            // 512x1024 bf16 (W_out^T)

  // weight transposes + dbl zero (independent of LN)
  transpose_cast_k<<<dim3(2048 / 32, 512 / 32), 256, 0, stream>>>(W_in, wt_in, 512, 2048);
  transpose_cast_k<<<dim3(64 / 32, 1024 / 32), 256, 0, stream>>>(W_x, wt_x, 1024, 64);
  transpose_cast_k<<<dim3(512 / 32, 1024 / 32), 256, 0, stream>>>(W_out, wt_out, 1024, 512);
  zero_k<<<(BL_ * 64) / 1024, 256, 0, stream>>>((float4*)dbl);
  // 1. LN1 -> bf16
  ln_k<false, __hip_bfloat16><<<BL_, 256, 0, stream>>>(x, nullptr, ln1w, ln1b, xnb);
  // 2. xz = xnb @ wt_in^T   (8192 x 2048 x 512) MFMA
  gemm_mfma_k<<<dim3(2048 / 128, BL_ / 128), 256, 0, stream>>>(xnb, wt_in, xz, BL_, 2048, 512);
  // 3. causal conv + silu -> bf16
  conv_silu_k<<<(BL_ * DIN_) / 256, 256, 0, stream>>>(xz, convw, convb, xcb);
  // 4. dbl += xcb @ wt_x^T  (8192 x 64 x 1024) MFMA split-K=4
  gemm_mfma_n64_k<<<dim3(4, BL_ / 128), 256, 0, stream>>>(xcb, wt_x, dbl, BL_, DIN_);
  // 5. dt = softplus(dt_r @ W_dt + b_dt)   (8192 x 1024 x 32) f32
  gemm_k<true><<<dim3(DIN_ / 64, BL_ / 64), 256, 0, stream>>>(
      dbl, W_dt, b_dt, dtb, BL_, DIN_, DTR, 64, DIN_, DIN_);
  // 6. chunked selective scan (P/S/h0 overlay r0; y overwrites xcb as bf16)
  scan1_k<<<B_ * 64 * NC_, 256, 0, stream>>>(dtb, dbl, A_log, xcb, Pb, Sb);
  comb_k<<<(B_ * DIN_ * NST) / 256, 256, 0, stream>>>(Pb, Sb, h0);
  scan3_k<<<B_ * 64 * NC_, 256, 0, stream>>>(dtb, dbl, A_log, Dskip, xz, h0, xcb);
  // 7. ymid = y @ wt_out^T  (8192 x 512 x 1024) MFMA (r0 free again)
  gemm_mfma_k<<<dim3(512 / 128, BL_ / 128), 256, 0, stream>>>(xcb, wt_out, ymid, BL_, 512, DIN_);
  // 8. out = LN2(x + ymid)
  ln_k<true, float><<<BL_, 256, 0, stream>>>(x, ymid, ln2w, ln2b, out);
}

// Round 4
// 351.178 us; speedup vs baseline: 4.0420x; 1.5650x over previous
//
#include <hip/hip_runtime.h>
#include <hip/hip_bf16.h>
#include <math.h>

// Problem constants (match reference)
constexpr int B_   = 8;
constexpr int L_   = 1024;
constexpr int D_   = 512;
constexpr int DIN_ = 1024;   // EXPAND * D
constexpr int NST  = 16;     // DSTATE
constexpr int DTR  = 32;     // DTRANK
constexpr int BL_  = B_ * L_;
constexpr int NC_  = 16;     // time chunks for parallel scan
constexpr int LC_  = L_ / NC_;  // 64 steps per chunk
#define EPSV 1e-5f

typedef __attribute__((ext_vector_type(8))) short short8;   // 8 bf16 = 4 VGPRs (MFMA A/B frag)
typedef __attribute__((ext_vector_type(4))) float f32x4;    // MFMA C/D frag

__device__ __forceinline__ float sigmoidf_(float x) { return 1.f / (1.f + expf(-x)); }
__device__ __forceinline__ float softplusf_(float x) { return fmaxf(x, 0.f) + log1pf(expf(-fabsf(x))); }

// async global->LDS, 16B per lane. LDS dest = wave-uniform base + lane*16.
__device__ __forceinline__ void gld16(const void* g, void* l) {
  __builtin_amdgcn_global_load_lds((const __attribute__((address_space(1))) void*)g,
                                   (__attribute__((address_space(3))) void*)l, 16, 0, 0);
}

// ---------------- LayerNorm over D_=512. block=256, 2 cols/thread. TO = float or bf16 out. ----
template <bool RES, typename TO>
__global__ __launch_bounds__(256) void ln_k(const float* __restrict__ x,
                                            const float* __restrict__ res,
                                            const float* __restrict__ w,
                                            const float* __restrict__ b,
                                            TO* __restrict__ out) {
  int row = blockIdx.x;
  int tid = threadIdx.x;
  const float* xr = x + (size_t)row * D_;
  float v0 = xr[tid], v1 = xr[tid + 256];
  if (RES) {
    const float* rr = res + (size_t)row * D_;
    v0 += rr[tid];
    v1 += rr[tid + 256];
  }
  float s = v0 + v1, ss = v0 * v0 + v1 * v1;
  __shared__ float r1[256], r2[256];
  r1[tid] = s; r2[tid] = ss;
  __syncthreads();
  for (int off = 128; off > 0; off >>= 1) {
    if (tid < off) { r1[tid] += r1[tid + off]; r2[tid] += r2[tid + off]; }
    __syncthreads();
  }
  float mean = r1[0] * (1.f / D_);
  float var  = r2[0] * (1.f / D_) - mean * mean;
  float rs   = rsqrtf(var + EPSV);
  float o0 = (v0 - mean) * rs * w[tid] + b[tid];
  float o1 = (v1 - mean) * rs * w[tid + 256] + b[tid + 256];
  TO* orow = out + (size_t)row * D_;
  if constexpr (sizeof(TO) == 2) {
    orow[tid]       = __float2bfloat16(o0);
    orow[tid + 256] = __float2bfloat16(o1);
  } else {
    orow[tid]       = o0;
    orow[tid + 256] = o1;
  }
}

// ---------------- transpose-cast: W (K x N, f32) -> Wt (N x K, bf16) ----------------
__global__ __launch_bounds__(256) void transpose_cast_k(const float* __restrict__ W,
                                                        __hip_bfloat16* __restrict__ Wt,
                                                        int K, int N) {
  __shared__ float t[32][33];
  int c = threadIdx.x & 31, r8 = threadIdx.x >> 5;  // 8 rows per pass
  int n0 = blockIdx.x * 32, k0 = blockIdx.y * 32;
#pragma unroll
  for (int rr = 0; rr < 4; rr++) {
    int k = k0 + r8 + rr * 8;
    t[r8 + rr * 8][c] = W[(size_t)k * N + n0 + c];
  }
  __syncthreads();
#pragma unroll
  for (int rr = 0; rr < 4; rr++) {
    int n = n0 + r8 + rr * 8;
    Wt[(size_t)n * K + k0 + c] = __float2bfloat16(t[c][r8 + rr * 8]);
  }
}

// ---------------- zero f32 buffer ----------------
__global__ __launch_bounds__(256) void zero_k(float4* __restrict__ p) {
  p[(size_t)blockIdx.x * 256 + threadIdx.x] = float4{0.f, 0.f, 0.f, 0.f};
}

// ---------------- bf16 MFMA GEMM: C(f32 MxN) = A(bf16 MxK) @ Bt(bf16 NxK)^T ------------
// 128x128 tile, BK=32, 256 thr = 4 waves (2x2 of 64x64). m97 structure.
__global__ __launch_bounds__(256) void gemm_mfma_k(const __hip_bfloat16* __restrict__ A,
                                                   const __hip_bfloat16* __restrict__ Bt,
                                                   float* __restrict__ C,
                                                   int M, int N, int K) {
  __shared__ __align__(16) __hip_bfloat16 As[128 * 32];
  __shared__ __align__(16) __hip_bfloat16 Bs[128 * 32];
  int tid = threadIdx.x, w = tid >> 6, l = tid & 63;
  int m0 = blockIdx.y * 128, n0 = blockIdx.x * 128;
  int wm = (w >> 1) * 64, wn = (w & 1) * 64;
  int m16 = l & 15, q = l >> 4;
  int lr = l >> 2, lc = (l & 3) * 8;  // staging: row-in-16, elem chunk
  f32x4 acc[4][4] = {};
  for (int k0 = 0; k0 < K; k0 += 32) {
#pragma unroll
    for (int p = 0; p < 2; p++) {
      int rg = p * 4 + w;  // row-group of 16 (0..7)
      gld16(A  + (size_t)(m0 + rg * 16 + lr) * K + k0 + lc, As + rg * 512);
      gld16(Bt + (size_t)(n0 + rg * 16 + lr) * K + k0 + lc, Bs + rg * 512);
    }
    __syncthreads();
    short8 av[4], bv[4];
#pragma unroll
    for (int i = 0; i < 4; i++)
      av[i] = *(const short8*)(As + (wm + i * 16 + m16) * 32 + q * 8);
#pragma unroll
    for (int j = 0; j < 4; j++)
      bv[j] = *(const short8*)(Bs + (wn + j * 16 + m16) * 32 + q * 8);
#pragma unroll
    for (int i = 0; i < 4; i++)
#pragma unroll
      for (int j = 0; j < 4; j++)
        acc[i][j] = __builtin_amdgcn_mfma_f32_16x16x32_bf16(av[i], bv[j], acc[i][j], 0, 0, 0);
    __syncthreads();
  }
  // C/D layout: col = lane&15, row = (lane>>4)*4 + r  [m89/m91 verified]
#pragma unroll
  for (int i = 0; i < 4; i++)
#pragma unroll
    for (int j = 0; j < 4; j++)
#pragma unroll
      for (int r = 0; r < 4; r++) {
        int gm = m0 + wm + i * 16 + q * 4 + r;
        int gn = n0 + wn + j * 16 + m16;
        C[(size_t)gm * N + gn] = acc[i][j][r];
      }
}

// ---- N=64 variant with split-K (for xp @ W_x): tile 128x64, grid=(SK, M/128), atomicAdd.
__global__ __launch_bounds__(256) void gemm_mfma_n64_k(const __hip_bfloat16* __restrict__ A,
                                                       const __hip_bfloat16* __restrict__ Bt,
                                                       float* __restrict__ C,
                                                       int M, int K) {
  __shared__ __align__(16) __hip_bfloat16 As[128 * 32];
  __shared__ __align__(16) __hip_bfloat16 Bs[64 * 32];
  int tid = threadIdx.x, w = tid >> 6, l = tid & 63;
  int m0 = blockIdx.y * 128;
  int kper = K / gridDim.x, kbeg = blockIdx.x * kper;
  int m16 = l & 15, q = l >> 4;
  int lr = l >> 2, lc = (l & 3) * 8;
  f32x4 acc[2][4] = {};
  for (int k0 = kbeg; k0 < kbeg + kper; k0 += 32) {
#pragma unroll
    for (int p = 0; p < 2; p++) {
      int rg = p * 4 + w;
      gld16(A + (size_t)(m0 + rg * 16 + lr) * K + k0 + lc, As + rg * 512);
    }
    gld16(Bt + (size_t)(w * 16 + lr) * K + k0 + lc, Bs + w * 512);
    __syncthreads();
    short8 av[2], bv[4];
#pragma unroll
    for (int i = 0; i < 2; i++)
      av[i] = *(const short8*)(As + (w * 32 + i * 16 + m16) * 32 + q * 8);
#pragma unroll
    for (int j = 0; j < 4; j++)
      bv[j] = *(const short8*)(Bs + (j * 16 + m16) * 32 + q * 8);
#pragma unroll
    for (int i = 0; i < 2; i++)
#pragma unroll
      for (int j = 0; j < 4; j++)
        acc[i][j] = __builtin_amdgcn_mfma_f32_16x16x32_bf16(av[i], bv[j], acc[i][j], 0, 0, 0);
    __syncthreads();
  }
#pragma unroll
  for (int i = 0; i < 2; i++)
#pragma unroll
    for (int j = 0; j < 4; j++)
#pragma unroll
      for (int r = 0; r < 4; r++) {
        int gm = m0 + w * 32 + i * 16 + q * 4 + r;
        int gn = j * 16 + m16;
        atomicAdd(&C[(size_t)gm * 64 + gn], acc[i][j][r]);
      }
}

// ---------------- Tiled f32 GEMM (kept for the tiny K=32 dt GEMM) ----------------
template <bool SP>
__global__ __launch_bounds__(256) void gemm_k(const float* __restrict__ A,
                                              const float* __restrict__ Bw,
                                              const float* __restrict__ bias,
                                              float* __restrict__ C,
                                              int M, int N, int K,
                                              int lda, int ldb, int ldc) {
  constexpr int BK = 16, LDP = 68;
  __shared__ float As[BK * LDP];
  __shared__ float Bs[BK * LDP];
  int tid = threadIdx.x;
  int m0 = blockIdx.y * 64, n0 = blockIdx.x * 64;
  int tn = tid & 15, tm = tid >> 4;
  int am = tid >> 2, ak = (tid & 3) * 4;
  int bn = tid & 63, bk = tid >> 6;
  float acc[4][4] = {};
  for (int k0 = 0; k0 < K; k0 += BK) {
    float4 av = *(const float4*)(A + (size_t)(m0 + am) * lda + k0 + ak);
    As[(ak + 0) * LDP + am] = av.x;
    As[(ak + 1) * LDP + am] = av.y;
    As[(ak + 2) * LDP + am] = av.z;
    As[(ak + 3) * LDP + am] = av.w;
#pragma unroll
    for (int i = 0; i < 4; i++)
      Bs[(bk + 4 * i) * LDP + bn] = Bw[(size_t)(k0 + bk + 4 * i) * ldb + n0 + bn];
    __syncthreads();
#pragma unroll
    for (int kk = 0; kk < BK; kk++) {
      float4 a4 = *(const float4*)(As + kk * LDP + tm * 4);
      float4 b4 = *(const float4*)(Bs + kk * LDP + tn * 4);
      float a[4] = {a4.x, a4.y, a4.z, a4.w};
      float bb[4] = {b4.x, b4.y, b4.z, b4.w};
#pragma unroll
      for (int i = 0; i < 4; i++)
#pragma unroll
        for (int j = 0; j < 4; j++) acc[i][j] = fmaf(a[i], bb[j], acc[i][j]);
    }
    __syncthreads();
  }
#pragma unroll
  for (int i = 0; i < 4; i++) {
    float v[4];
#pragma unroll
    for (int j = 0; j < 4; j++) {
      float t = acc[i][j];
      if (SP) t = softplusf_(t + bias[n0 + tn * 4 + j]);
      v[j] = t;
    }
    float4 o = {v[0], v[1], v[2], v[3]};
    *(float4*)(C + (size_t)(m0 + tm * 4 + i) * ldc + n0 + tn * 4) = o;
  }
}

// ---------------- Causal depthwise conv (k=4) + bias + SiLU -> bf16 ----------------
__global__ __launch_bounds__(256) void conv_silu_k(const float* __restrict__ xz,
                                                   const float* __restrict__ cw,
                                                   const float* __restrict__ cb,
                                                   __hip_bfloat16* __restrict__ xcb) {
  int idx = blockIdx.x * 256 + threadIdx.x;  // over BL_*DIN_
  int d  = idx & (DIN_ - 1);
  int bl = idx >> 10;
  int t  = bl & (L_ - 1);
  float acc = cb[d];
#pragma unroll
  for (int j = 0; j < 4; j++) {
    int tt = t - 3 + j;
    if (tt >= 0) acc = fmaf(xz[(size_t)(bl + tt - t) * (2 * DIN_) + d], cw[d * 4 + j], acc);
  }
  xcb[idx] = __float2bfloat16(acc * sigmoidf_(acc));
}

// ---------------- Chunked selective scan, 4 states per lane ----------------
// wave = 16 d (dl) x 4 lane-groups (nq); each lane owns n = nq*4 .. nq*4+3.
// block = 256 thr = 64 d per (b,c). grid = B * NC * (DIN/64) = 2048 blocks.
// Per-step loads: dt, xv scalar; B (and C) as float4. Pointer-increment addressing;
// the final prefetch overreaches one row into the NEXT ws buffer (valid mem, discarded).
// Pass 1: P = exp2(A2 * sum(dt)) [A2 = -exp(A_log)*log2e], S = local scan from 0.
__global__ __launch_bounds__(256) void scan1_k(const float* __restrict__ dt,
                                               const float* __restrict__ dbl,
                                               const float* __restrict__ A_log,
                                               const __hip_bfloat16* __restrict__ xcb,
                                               float* __restrict__ Pb,
                                               float* __restrict__ Sb) {
  constexpr float LOG2E = 1.4426950408889634f;
  int lane = threadIdx.x & 63, wv = threadIdx.x >> 6;
  int dl = lane >> 2, nq = lane & 3;
  int dg = blockIdx.x & 15;
  int c  = (blockIdx.x >> 4) & (NC_ - 1);
  int b  = blockIdx.x >> 8;
  int d  = dg * 64 + wv * 16 + dl;
  float4 Al = *(const float4*)(A_log + d * NST + nq * 4);
  float Ad[4] = {-expf(Al.x) * LOG2E, -expf(Al.y) * LOG2E,
                 -expf(Al.z) * LOG2E, -expf(Al.w) * LOG2E};
  size_t row0 = (size_t)b * L_ + (size_t)c * LC_;
  const float* pdt = dt + row0 * DIN_ + d;
  const __hip_bfloat16* pxv = xcb + row0 * DIN_ + d;
  const float* pB = dbl + row0 * 64 + 32 + nq * 4;
  float dtv = *pdt;
  float xv  = __bfloat162float(*pxv);
  float4 Bn = *(const float4*)pB;
  float Ts = 0.f;
  float S[4] = {0.f, 0.f, 0.f, 0.f};
  for (int t = 0; t < LC_; ++t) {
    pdt += DIN_; pxv += DIN_; pB += 64;
    float dtv2 = *pdt;
    float xv2  = __bfloat162float(*pxv);
    float4 Bn2 = *(const float4*)pB;
    float dtx = dtv * xv;
    Ts += dtv;
    float Ba[4] = {Bn.x, Bn.y, Bn.z, Bn.w};
#pragma unroll
    for (int j = 0; j < 4; j++) {
      float dA = __builtin_amdgcn_exp2f(dtv * Ad[j]);
      S[j] = fmaf(dA, S[j], dtx * Ba[j]);
    }
    dtv = dtv2; xv = xv2; Bn = Bn2;
  }
  size_t idx = ((size_t)(b * NC_ + c) * DIN_ + d) * NST + nq * 4;
  *(float4*)(Pb + idx) = float4{__builtin_amdgcn_exp2f(Ts * Ad[0]),
                                __builtin_amdgcn_exp2f(Ts * Ad[1]),
                                __builtin_amdgcn_exp2f(Ts * Ad[2]),
                                __builtin_amdgcn_exp2f(Ts * Ad[3])};
  *(float4*)(Sb + idx) = float4{S[0], S[1], S[2], S[3]};
}

// Pass 2: sequential combine over NC_ chunks -> per-chunk initial state h0.
__global__ __launch_bounds__(256) void comb_k(const float* __restrict__ Pb,
                                              const float* __restrict__ Sb,
                                              float* __restrict__ h0) {
  int gid = blockIdx.x * 256 + threadIdx.x;  // over B_*DIN_*NST
  int b   = gid >> 14;
  int rem = gid & (DIN_ * NST - 1);
  float h = 0.f;
#pragma unroll
  for (int c = 0; c < NC_; ++c) {
    size_t idx = (size_t)(b * NC_ + c) * DIN_ * NST + rem;
    h0[idx] = h;
    h = fmaf(Pb[idx], h, Sb[idx]);
  }
}

// Pass 3: re-run chunk from h0, emit gated y as bf16 IN PLACE over xcb.
// Safe: prefetch of row t+1 is issued before the (nq==0) store to row t; addresses differ.
__global__ __launch_bounds__(256) void scan3_k(const float* __restrict__ dt,
                                               const float* __restrict__ dbl,
                                               const float* __restrict__ A_log,
                                               const float* __restrict__ Dskip,
                                               const float* __restrict__ xz,
                                               const float* __restrict__ h0,
                                               __hip_bfloat16* __restrict__ xcb) {
  constexpr float LOG2E = 1.4426950408889634f;
  int lane = threadIdx.x & 63, wv = threadIdx.x >> 6;
  int dl = lane >> 2, nq = lane & 3;
  int dg = blockIdx.x & 15;
  int c  = (blockIdx.x >> 4) & (NC_ - 1);
  int b  = blockIdx.x >> 8;
  int d  = dg * 64 + wv * 16 + dl;
  float4 Al = *(const float4*)(A_log + d * NST + nq * 4);
  float Ad[4] = {-expf(Al.x) * LOG2E, -expf(Al.y) * LOG2E,
                 -expf(Al.z) * LOG2E, -expf(Al.w) * LOG2E};
  float Dd = Dskip[d];
  size_t sidx = ((size_t)(b * NC_ + c) * DIN_ + d) * NST + nq * 4;
  float4 h4 = *(const float4*)(h0 + sidx);
  float h[4] = {h4.x, h4.y, h4.z, h4.w};
  size_t row0 = (size_t)b * L_ + (size_t)c * LC_;
  const float* pdt = dt + row0 * DIN_ + d;
  const __hip_bfloat16* pxv = xcb + row0 * DIN_ + d;
  const float* pBC = dbl + row0 * 64 + nq * 4;
  const float* pz  = xz + row0 * 2 * DIN_ + DIN_ + d;
  __hip_bfloat16* py = xcb + row0 * DIN_ + d;
  float dtv = *pdt;
  float xv  = __bfloat162float(*pxv);
  float4 Bn = *(const float4*)(pBC + 32);
  float4 Cn = *(const float4*)(pBC + 48);
  float zv  = *pz;
  for (int t = 0; t < LC_; ++t) {
    pdt += DIN_; pxv += DIN_; pBC += 64; pz += 2 * DIN_;
    float dtv2 = *pdt;
    float xv2  = __bfloat162float(*pxv);
    float4 Bn2 = *(const float4*)(pBC + 32);
    float4 Cn2 = *(const float4*)(pBC + 48);
    float zv2  = *pz;
    float dtx = dtv * xv;
    float Ba[4] = {Bn.x, Bn.y, Bn.z, Bn.w};
    float Ca[4] = {Cn.x, Cn.y, Cn.z, Cn.w};
    float p = 0.f;
#pragma unroll
    for (int j = 0; j < 4; j++) {
      float dA = __builtin_amdgcn_exp2f(dtv * Ad[j]);
      h[j] = fmaf(dA, h[j], dtx * Ba[j]);
      p = fmaf(h[j], Ca[j], p);
    }
    p += __shfl_xor(p, 1, 4);
    p += __shfl_xor(p, 2, 4);
    if (nq == 0) {
      float sg = __builtin_amdgcn_rcpf(1.f + __builtin_amdgcn_exp2f(-zv * LOG2E));
      *py = __float2bfloat16((p + xv * Dd) * (zv * sg));
    }
    py += DIN_;
    dtv = dtv2; xv = xv2; Bn = Bn2; Cn = Cn2; zv = zv2;
  }
}

extern "C" void kernel_launch(void* const* d_in, const int* in_sizes, int n_in,
                              void* d_out, int out_size, void* d_ws, size_t ws_size,
                              hipStream_t stream) {
  const float* x     = (const float*)d_in[0];
  const float* ln1w  = (const float*)d_in[1];
  const float* ln1b  = (const float*)d_in[2];
  const float* W_in  = (const float*)d_in[3];
  const float* convw = (const float*)d_in[4];
  const float* convb = (const float*)d_in[5];
  const float* W_x   = (const float*)d_in[6];
  const float* W_dt  = (const float*)d_in[7];
  const float* b_dt  = (const float*)d_in[8];
  const float* A_log = (const float*)d_in[9];
  const float* Dskip = (const float*)d_in[10];
  const float* W_out = (const float*)d_in[11];
  const float* ln2w  = (const float*)d_in[12];
  const float* ln2b  = (const float*)d_in[13];
  float* out = (float*)d_out;

  // Workspace layout: 141.125 MiB total (proven budget >= 146 MiB from round 1).
  float* ws  = (float*)d_ws;
  float* xz  = ws;                            // BL*2048 f32 (xp | z)              64 MiB
  float* dtb = xz + (size_t)BL_ * 2 * DIN_;   // BL*1024 f32 (softplus dt)         32 MiB
  float* dbl = dtb + (size_t)BL_ * DIN_;      // BL*64  f32 (dt_r | B | C)          2 MiB
  float* r0  = dbl + (size_t)BL_ * 64;        // 4M f32, time-multiplexed:         16 MiB
  //   r0 as bf16 xnb [LN1->GEMM1], as P/S [scan1->comb], as f32 ymid [GEMM7->LN2]
  __hip_bfloat16* xnb = (__hip_bfloat16*)r0;            // BL*512 bf16
  constexpr size_t PSZ = (size_t)B_ * NC_ * DIN_ * NST; // 2M floats
  float* Pb = r0;
  float* Sb = r0 + PSZ;
  float* ymid = r0;                                     // BL*512 f32
  __hip_bfloat16* xcb = (__hip_bfloat16*)(r0 + (size_t)BL_ * D_);  // BL*1024 bf16   16 MiB
  __hip_bfloat16* wt_in  = xcb + (size_t)BL_ * DIN_;    // 2048x512 bf16              2 MiB
  __hip_bfloat16* wt_x   = wt_in + 2048 * 512;          // 64x1024 bf16           0.125 MiB
  __hip_bfloat16* wt_out = wt_x + 64 * 1024;            // 512x1024 bf16              1 MiB
  float* h0 = (float*)(wt_out + 512 * 1024);            // 2M f32 (chunk init states) 8 MiB

  // weight transposes + dbl zero (independent of LN)
  transpose_cast_k<<<dim3(2048 / 32, 512 / 32), 256, 0, stream>>>(W_in, wt_in, 512, 2048);
  transpose_cast_k<<<dim3(64 / 32, 1024 / 32), 256, 0, stream>>>(W_x, wt_x, 1024, 64);
  transpose_cast_k<<<dim3(512 / 32, 1024 / 32), 256, 0, stream>>>(W_out, wt_out, 1024, 512);
  zero_k<<<(BL_ * 64) / 1024, 256, 0, stream>>>((float4*)dbl);
  // 1. LN1 -> bf16
  ln_k<false, __hip_bfloat16><<<BL_, 256, 0, stream>>>(x, nullptr, ln1w, ln1b, xnb);
  // 2. xz = xnb @ wt_in^T   (8192 x 2048 x 512) MFMA
  gemm_mfma_k<<<dim3(2048 / 128, BL_ / 128), 256, 0, stream>>>(xnb, wt_in, xz, BL_, 2048, 512);
  // 3. causal conv + silu -> bf16
  conv_silu_k<<<(BL_ * DIN_) / 256, 256, 0, stream>>>(xz, convw, convb, xcb);
  // 4. dbl += xcb @ wt_x^T  (8192 x 64 x 1024) MFMA split-K=4
  gemm_mfma_n64_k<<<dim3(4, BL_ / 128), 256, 0, stream>>>(xcb, wt_x, dbl, BL_, DIN_);
  // 5. dt = softplus(dt_r @ W_dt + b_dt)   (8192 x 1024 x 32) f32
  gemm_k<true><<<dim3(DIN_ / 64, BL_ / 64), 256, 0, stream>>>(
      dbl, W_dt, b_dt, dtb, BL_, DIN_, DTR, 64, DIN_, DIN_);
  // 6. chunked selective scan (P/S overlay r0; h0 in tail; y overwrites xcb as bf16)
  scan1_k<<<B_ * NC_ * (DIN_ / 64), 256, 0, stream>>>(dtb, dbl, A_log, xcb, Pb, Sb);
  comb_k<<<(B_ * DIN_ * NST) / 256, 256, 0, stream>>>(Pb, Sb, h0);
  scan3_k<<<B_ * NC_ * (DIN_ / 64), 256, 0, stream>>>(dtb, dbl, A_log, Dskip, xz, h0, xcb);
  // 7. ymid = y @ wt_out^T  (8192 x 512 x 1024) MFMA (r0 free again)
  gemm_mfma_k<<<dim3(512 / 128, BL_ / 128), 256, 0, stream>>>(xcb, wt_out, ymid, BL_, 512, DIN_);
  // 8. out = LN2(x + ymid)
  ln_k<true, float><<<BL_, 256, 0, stream>>>(x, ymid, ln2w, ln2b, out);
}

// Round 5
// 317.908 us; speedup vs baseline: 4.4651x; 1.1047x over previous
//
#include <hip/hip_runtime.h>
#include <hip/hip_bf16.h>
#include <math.h>

// Problem constants (match reference)
constexpr int B_   = 8;
constexpr int L_   = 1024;
constexpr int D_   = 512;
constexpr int DIN_ = 1024;   // EXPAND * D
constexpr int NST  = 16;     // DSTATE
constexpr int DTR  = 32;     // DTRANK
constexpr int BL_  = B_ * L_;
constexpr int NC_  = 16;     // time chunks for parallel scan
constexpr int LC_  = L_ / NC_;  // 64 steps per chunk
#define EPSV 1e-5f
constexpr float LOG2E_ = 1.4426950408889634f;

typedef __attribute__((ext_vector_type(8))) short short8;   // 8 bf16 = 4 VGPRs (MFMA A/B frag)
typedef __attribute__((ext_vector_type(4))) float f32x4;    // MFMA C/D frag

__device__ __forceinline__ float fsig(float x) {   // fast sigmoid (exp2+rcp)
  return __builtin_amdgcn_rcpf(1.f + __builtin_amdgcn_exp2f(-x * LOG2E_));
}
__device__ __forceinline__ float softplusf_(float x) { return fmaxf(x, 0.f) + log1pf(expf(-fabsf(x))); }

// async global->LDS, 16B per lane. LDS dest = wave-uniform base + lane*16.
__device__ __forceinline__ void gld16(const void* g, void* l) {
  __builtin_amdgcn_global_load_lds((const __attribute__((address_space(1))) void*)g,
                                   (__attribute__((address_space(3))) void*)l, 16, 0, 0);
}

// ---------------- LayerNorm over D_=512. block=256, 2 cols/thread. ----------------
template <bool RES, typename TO>
__global__ __launch_bounds__(256) void ln_k(const float* __restrict__ x,
                                            const float* __restrict__ res,
                                            const float* __restrict__ w,
                                            const float* __restrict__ b,
                                            TO* __restrict__ out) {
  int row = blockIdx.x;
  int tid = threadIdx.x;
  const float* xr = x + (size_t)row * D_;
  float v0 = xr[tid], v1 = xr[tid + 256];
  if (RES) {
    const float* rr = res + (size_t)row * D_;
    v0 += rr[tid];
    v1 += rr[tid + 256];
  }
  float s = v0 + v1, ss = v0 * v0 + v1 * v1;
  __shared__ float r1[256], r2[256];
  r1[tid] = s; r2[tid] = ss;
  __syncthreads();
  for (int off = 128; off > 0; off >>= 1) {
    if (tid < off) { r1[tid] += r1[tid + off]; r2[tid] += r2[tid + off]; }
    __syncthreads();
  }
  float mean = r1[0] * (1.f / D_);
  float var  = r2[0] * (1.f / D_) - mean * mean;
  float rs   = rsqrtf(var + EPSV);
  float o0 = (v0 - mean) * rs * w[tid] + b[tid];
  float o1 = (v1 - mean) * rs * w[tid + 256] + b[tid + 256];
  TO* orow = out + (size_t)row * D_;
  if constexpr (sizeof(TO) == 2) {
    orow[tid]       = __float2bfloat16(o0);
    orow[tid + 256] = __float2bfloat16(o1);
  } else {
    orow[tid]       = o0;
    orow[tid + 256] = o1;
  }
}

// ---------------- transpose-cast: W (K x N, f32) -> Wt (N x K, bf16) ----------------
__global__ __launch_bounds__(256) void transpose_cast_k(const float* __restrict__ W,
                                                        __hip_bfloat16* __restrict__ Wt,
                                                        int K, int N) {
  __shared__ float t[32][33];
  int c = threadIdx.x & 31, r8 = threadIdx.x >> 5;
  int n0 = blockIdx.x * 32, k0 = blockIdx.y * 32;
#pragma unroll
  for (int rr = 0; rr < 4; rr++) {
    int k = k0 + r8 + rr * 8;
    t[r8 + rr * 8][c] = W[(size_t)k * N + n0 + c];
  }
  __syncthreads();
#pragma unroll
  for (int rr = 0; rr < 4; rr++) {
    int n = n0 + r8 + rr * 8;
    Wt[(size_t)n * K + k0 + c] = __float2bfloat16(t[c][r8 + rr * 8]);
  }
}

// ---------------- zero f32 buffer ----------------
__global__ __launch_bounds__(256) void zero_k(float4* __restrict__ p) {
  p[(size_t)blockIdx.x * 256 + threadIdx.x] = float4{0.f, 0.f, 0.f, 0.f};
}

// ---------------- bf16 MFMA GEMM: 128x128 tile, BK=32, 4 waves. ------------
// EPI=0: plain f32 store to C. EPI=1 (the in-proj GEMM, N=2048): xp half -> bf16 XP;
// z half -> g = z*sigmoid(z) bf16 into Gb (z never materialized in f32).
template <int EPI>
__global__ __launch_bounds__(256) void gemm_mfma_k(const __hip_bfloat16* __restrict__ A,
                                                   const __hip_bfloat16* __restrict__ Bt,
                                                   float* __restrict__ C,
                                                   __hip_bfloat16* __restrict__ XP,
                                                   __hip_bfloat16* __restrict__ Gb,
                                                   int M, int N, int K) {
  __shared__ __align__(16) __hip_bfloat16 As[128 * 32];
  __shared__ __align__(16) __hip_bfloat16 Bs[128 * 32];
  int tid = threadIdx.x, w = tid >> 6, l = tid & 63;
  int m0 = blockIdx.y * 128, n0 = blockIdx.x * 128;
  int wm = (w >> 1) * 64, wn = (w & 1) * 64;
  int m16 = l & 15, q = l >> 4;
  int lr = l >> 2, lc = (l & 3) * 8;
  f32x4 acc[4][4] = {};
  for (int k0 = 0; k0 < K; k0 += 32) {
#pragma unroll
    for (int p = 0; p < 2; p++) {
      int rg = p * 4 + w;
      gld16(A  + (size_t)(m0 + rg * 16 + lr) * K + k0 + lc, As + rg * 512);
      gld16(Bt + (size_t)(n0 + rg * 16 + lr) * K + k0 + lc, Bs + rg * 512);
    }
    __syncthreads();
    short8 av[4], bv[4];
#pragma unroll
    for (int i = 0; i < 4; i++)
      av[i] = *(const short8*)(As + (wm + i * 16 + m16) * 32 + q * 8);
#pragma unroll
    for (int j = 0; j < 4; j++)
      bv[j] = *(const short8*)(Bs + (wn + j * 16 + m16) * 32 + q * 8);
#pragma unroll
    for (int i = 0; i < 4; i++)
#pragma unroll
      for (int j = 0; j < 4; j++)
        acc[i][j] = __builtin_amdgcn_mfma_f32_16x16x32_bf16(av[i], bv[j], acc[i][j], 0, 0, 0);
    __syncthreads();
  }
  // C/D layout: col = lane&15, row = (lane>>4)*4 + r  [m89/m91 verified]
  if (EPI == 0) {
#pragma unroll
    for (int i = 0; i < 4; i++)
#pragma unroll
      for (int j = 0; j < 4; j++)
#pragma unroll
        for (int r = 0; r < 4; r++) {
          int gm = m0 + wm + i * 16 + q * 4 + r;
          int gn = n0 + wn + j * 16 + m16;
          C[(size_t)gm * N + gn] = acc[i][j][r];
        }
  } else {
    bool isz = (n0 >= DIN_);             // uniform per block (128 | 1024)
    int colbase = n0 - (isz ? DIN_ : 0);
#pragma unroll
    for (int i = 0; i < 4; i++)
#pragma unroll
      for (int j = 0; j < 4; j++)
#pragma unroll
        for (int r = 0; r < 4; r++) {
          int gm = m0 + wm + i * 16 + q * 4 + r;
          int cl = colbase + wn + j * 16 + m16;
          float v = acc[i][j][r];
          if (!isz) XP[(size_t)gm * DIN_ + cl] = __float2bfloat16(v);
          else      Gb[(size_t)gm * DIN_ + cl] = __float2bfloat16(v * fsig(v));
        }
  }
}

// ---- N=64 variant with split-K (for xp @ W_x): tile 128x64, grid=(SK, M/128), atomicAdd.
__global__ __launch_bounds__(256) void gemm_mfma_n64_k(const __hip_bfloat16* __restrict__ A,
                                                       const __hip_bfloat16* __restrict__ Bt,
                                                       float* __restrict__ C,
                                                       int M, int K) {
  __shared__ __align__(16) __hip_bfloat16 As[128 * 32];
  __shared__ __align__(16) __hip_bfloat16 Bs[64 * 32];
  int tid = threadIdx.x, w = tid >> 6, l = tid & 63;
  int m0 = blockIdx.y * 128;
  int kper = K / gridDim.x, kbeg = blockIdx.x * kper;
  int m16 = l & 15, q = l >> 4;
  int lr = l >> 2, lc = (l & 3) * 8;
  f32x4 acc[2][4] = {};
  for (int k0 = kbeg; k0 < kbeg + kper; k0 += 32) {
#pragma unroll
    for (int p = 0; p < 2; p++) {
      int rg = p * 4 + w;
      gld16(A + (size_t)(m0 + rg * 16 + lr) * K + k0 + lc, As + rg * 512);
    }
    gld16(Bt + (size_t)(w * 16 + lr) * K + k0 + lc, Bs + w * 512);
    __syncthreads();
    short8 av[2], bv[4];
#pragma unroll
    for (int i = 0; i < 2; i++)
      av[i] = *(const short8*)(As + (w * 32 + i * 16 + m16) * 32 + q * 8);
#pragma unroll
    for (int j = 0; j < 4; j++)
      bv[j] = *(const short8*)(Bs + (j * 16 + m16) * 32 + q * 8);
#pragma unroll
    for (int i = 0; i < 2; i++)
#pragma unroll
      for (int j = 0; j < 4; j++)
        acc[i][j] = __builtin_amdgcn_mfma_f32_16x16x32_bf16(av[i], bv[j], acc[i][j], 0, 0, 0);
    __syncthreads();
  }
#pragma unroll
  for (int i = 0; i < 2; i++)
#pragma unroll
    for (int j = 0; j < 4; j++)
#pragma unroll
      for (int r = 0; r < 4; r++) {
        int gm = m0 + w * 32 + i * 16 + q * 4 + r;
        int gn = j * 16 + m16;
        atomicAdd(&C[(size_t)gm * 64 + gn], acc[i][j][r]);
      }
}

// ---------------- dt GEMM (8192x1024x32, f32) + softplus + pk=(dt, dt*xv) epilogue -------
__global__ __launch_bounds__(256) void gemm_dt_k(const float* __restrict__ A,   // dbl, lda=64
                                                 const float* __restrict__ Bw,  // W_dt [32][1024]
                                                 const float* __restrict__ bias,
                                                 const __hip_bfloat16* __restrict__ xcb,
                                                 float* __restrict__ pk) {      // [BL][DIN] float2
  constexpr int BK = 16, LDP = 68;
  __shared__ float As[BK * LDP];
  __shared__ float Bs[BK * LDP];
  int tid = threadIdx.x;
  int m0 = blockIdx.y * 64, n0 = blockIdx.x * 64;
  int tn = tid & 15, tm = tid >> 4;
  int am = tid >> 2, ak = (tid & 3) * 4;
  int bn = tid & 63, bk = tid >> 6;
  float acc[4][4] = {};
  for (int k0 = 0; k0 < DTR; k0 += BK) {
    float4 av = *(const float4*)(A + (size_t)(m0 + am) * 64 + k0 + ak);
    As[(ak + 0) * LDP + am] = av.x;
    As[(ak + 1) * LDP + am] = av.y;
    As[(ak + 2) * LDP + am] = av.z;
    As[(ak + 3) * LDP + am] = av.w;
#pragma unroll
    for (int i = 0; i < 4; i++)
      Bs[(bk + 4 * i) * LDP + bn] = Bw[(size_t)(k0 + bk + 4 * i) * DIN_ + n0 + bn];
    __syncthreads();
#pragma unroll
    for (int kk = 0; kk < BK; kk++) {
      float4 a4 = *(const float4*)(As + kk * LDP + tm * 4);
      float4 b4 = *(const float4*)(Bs + kk * LDP + tn * 4);
      float a[4] = {a4.x, a4.y, a4.z, a4.w};
      float bb[4] = {b4.x, b4.y, b4.z, b4.w};
#pragma unroll
      for (int i = 0; i < 4; i++)
#pragma unroll
        for (int j = 0; j < 4; j++) acc[i][j] = fmaf(a[i], bb[j], acc[i][j]);
    }
    __syncthreads();
  }
#pragma unroll
  for (int i = 0; i < 4; i++) {
    int gm = m0 + tm * 4 + i;
    int gn = n0 + tn * 4;
    float o[8];
#pragma unroll
    for (int j = 0; j < 4; j++) {
      float tv = softplusf_(acc[i][j] + bias[gn + j]);
      float xv = __bfloat162float(xcb[(size_t)gm * DIN_ + gn + j]);
      o[2 * j]     = tv;
      o[2 * j + 1] = tv * xv;
    }
    float* pout = pk + 2 * ((size_t)gm * DIN_ + gn);
    *(float4*)pout       = float4{o[0], o[1], o[2], o[3]};
    *(float4*)(pout + 4) = float4{o[4], o[5], o[6], o[7]};
  }
}

// ---------------- Causal depthwise conv (k=4) + bias + SiLU; 2 channels/thread -------
// Also packs gate pair PKG = (g, xv*D*g) bf16x2 per (t,d), consuming g from Gb.
__global__ __launch_bounds__(256) void conv_silu_k(const __hip_bfloat16* __restrict__ XP,
                                                   const __hip_bfloat16* __restrict__ Gb,
                                                   const float* __restrict__ cw,
                                                   const float* __restrict__ cb,
                                                   const float* __restrict__ Dsk,
                                                   __hip_bfloat16* __restrict__ xcb,
                                                   __hip_bfloat162* __restrict__ PKG) {
  int idx = blockIdx.x * 256 + threadIdx.x;  // over BL_*512 channel pairs
  int dp = idx & 511;
  int d  = dp * 2;
  int bl = idx >> 9;
  int t  = bl & (L_ - 1);
  float4 w0 = *(const float4*)(cw + d * 4);
  float4 w1 = *(const float4*)(cw + d * 4 + 4);
  float w0a[4] = {w0.x, w0.y, w0.z, w0.w};
  float w1a[4] = {w1.x, w1.y, w1.z, w1.w};
  float a0 = cb[d], a1 = cb[d + 1];
#pragma unroll
  for (int j = 0; j < 4; j++) {
    int tt = t - 3 + j;
    if (tt >= 0) {
      __hip_bfloat162 xp2 = *(const __hip_bfloat162*)(XP + (size_t)(bl + j - 3) * DIN_ + d);
      float2 xf = __bfloat1622float2(xp2);
      a0 = fmaf(xf.x, w0a[j], a0);
      a1 = fmaf(xf.y, w1a[j], a1);
    }
  }
  float xv0 = a0 * fsig(a0), xv1 = a1 * fsig(a1);
  __hip_bfloat162 xo;
  xo.x = __float2bfloat16(xv0); xo.y = __float2bfloat16(xv1);
  *(__hip_bfloat162*)(xcb + (size_t)bl * DIN_ + d) = xo;
  __hip_bfloat162 g2 = *(const __hip_bfloat162*)(Gb + (size_t)bl * DIN_ + d);
  float2 gf = __bfloat1622float2(g2);
  __hip_bfloat162 o0, o1;
  o0.x = g2.x; o0.y = __float2bfloat16(xv0 * Dsk[d] * gf.x);
  o1.x = g2.y; o1.y = __float2bfloat16(xv1 * Dsk[d + 1] * gf.y);
  PKG[(size_t)bl * DIN_ + d]     = o0;
  PKG[(size_t)bl * DIN_ + d + 1] = o1;
}

// ---------------- Chunked selective scan: ONE LANE = ONE d, 16 states in regs ----------
// B (and C) addresses are block-uniform -> scalar loads (off the VALU).
// grid = B * NC * (DIN/256) = 512 blocks. Double-buffered prefetch, 1-row overreach
// at chunk end lands inside d_ws (value discarded).
__global__ __launch_bounds__(256) void scan1_k(const float2* __restrict__ pk,
                                               const float* __restrict__ dbl,
                                               const float* __restrict__ A_log,
                                               float* __restrict__ Pb,
                                               float* __restrict__ Sb) {
  int tid = threadIdx.x, bx = blockIdx.x;
  int d = (bx & 3) * 256 + tid;
  int c = (bx >> 2) & (NC_ - 1);
  int b = bx >> 6;
  float Ad[16];
#pragma unroll
  for (int jj = 0; jj < 4; jj++) {
    float4 a4 = *(const float4*)(A_log + d * NST + jj * 4);
    Ad[jj * 4 + 0] = -expf(a4.x) * LOG2E_;
    Ad[jj * 4 + 1] = -expf(a4.y) * LOG2E_;
    Ad[jj * 4 + 2] = -expf(a4.z) * LOG2E_;
    Ad[jj * 4 + 3] = -expf(a4.w) * LOG2E_;
  }
  size_t row0 = (size_t)b * L_ + (size_t)c * LC_;
  const float2* ppk = pk + row0 * DIN_ + d;
  const float* pB = dbl + row0 * 64 + 32;
  float2 p0 = *ppk, p1;
  float B0[16], B1[16];
#pragma unroll
  for (int jj = 0; jj < 4; jj++) ((float4*)B0)[jj] = ((const float4*)pB)[jj];
  float S[16] = {};
  float Ts = 0.f;
  for (int t = 0; t < LC_; t += 2) {
    ppk += DIN_; pB += 64;
    p1 = *ppk;
#pragma unroll
    for (int jj = 0; jj < 4; jj++) ((float4*)B1)[jj] = ((const float4*)pB)[jj];
    Ts += p0.x;
#pragma unroll
    for (int j = 0; j < 16; j++) {
      float dA = __builtin_amdgcn_exp2f(p0.x * Ad[j]);
      S[j] = fmaf(dA, S[j], p0.y * B0[j]);
    }
    ppk += DIN_; pB += 64;
    p0 = *ppk;
#pragma unroll
    for (int jj = 0; jj < 4; jj++) ((float4*)B0)[jj] = ((const float4*)pB)[jj];
    Ts += p1.x;
#pragma unroll
    for (int j = 0; j < 16; j++) {
      float dA = __builtin_amdgcn_exp2f(p1.x * Ad[j]);
      S[j] = fmaf(dA, S[j], p1.y * B1[j]);
    }
  }
  size_t oidx = ((size_t)(b * NC_ + c) * DIN_ + d) * NST;
#pragma unroll
  for (int jj = 0; jj < 4; jj++) {
    float4 Pv = {__builtin_amdgcn_exp2f(Ts * Ad[jj * 4 + 0]),
                 __builtin_amdgcn_exp2f(Ts * Ad[jj * 4 + 1]),
                 __builtin_amdgcn_exp2f(Ts * Ad[jj * 4 + 2]),
                 __builtin_amdgcn_exp2f(Ts * Ad[jj * 4 + 3])};
    *(float4*)(Pb + oidx + jj * 4) = Pv;
    *(float4*)(Sb + oidx + jj * 4) = float4{S[jj * 4 + 0], S[jj * 4 + 1],
                                            S[jj * 4 + 2], S[jj * 4 + 3]};
  }
}

// Pass 2: sequential combine over NC_ chunks -> per-chunk initial state h0.
__global__ __launch_bounds__(256) void comb_k(const float* __restrict__ Pb,
                                              const float* __restrict__ Sb,
                                              float* __restrict__ h0) {
  int gid = blockIdx.x * 256 + threadIdx.x;  // over B_*DIN_*NST
  int b   = gid >> 14;
  int rem = gid & (DIN_ * NST - 1);
  float h = 0.f;
#pragma unroll
  for (int c = 0; c < NC_; ++c) {
    size_t idx = (size_t)(b * NC_ + c) * DIN_ * NST + rem;
    h0[idx] = h;
    h = fmaf(Pb[idx], h, Sb[idx]);
  }
}

// Pass 3: re-run chunk from h0; y = p*g + skipg (gate pair precomputed); bf16 y over xcb.
// scan3 never reads xcb -> no in-place hazard at all.
__global__ __launch_bounds__(256) void scan3_k(const float2* __restrict__ pk,
                                               const float* __restrict__ dbl,
                                               const float* __restrict__ A_log,
                                               const __hip_bfloat162* __restrict__ PKG,
                                               const float* __restrict__ h0,
                                               __hip_bfloat16* __restrict__ xcb) {
  int tid = threadIdx.x, bx = blockIdx.x;
  int d = (bx & 3) * 256 + tid;
  int c = (bx >> 2) & (NC_ - 1);
  int b = bx >> 6;
  float Ad[16];
#pragma unroll
  for (int jj = 0; jj < 4; jj++) {
    float4 a4 = *(const float4*)(A_log + d * NST + jj * 4);
    Ad[jj * 4 + 0] = -expf(a4.x) * LOG2E_;
    Ad[jj * 4 + 1] = -expf(a4.y) * LOG2E_;
    Ad[jj * 4 + 2] = -expf(a4.z) * LOG2E_;
    Ad[jj * 4 + 3] = -expf(a4.w) * LOG2E_;
  }
  size_t oidx = ((size_t)(b * NC_ + c) * DIN_ + d) * NST;
  float h[16];
#pragma unroll
  for (int jj = 0; jj < 4; jj++) ((float4*)h)[jj] = *(const float4*)(h0 + oidx + jj * 4);
  size_t row0 = (size_t)b * L_ + (size_t)c * LC_;
  const float2* ppk = pk + row0 * DIN_ + d;
  const float* pBC = dbl + row0 * 64;
  const __hip_bfloat162* pg = PKG + row0 * DIN_ + d;
  __hip_bfloat16* py = xcb + row0 * DIN_ + d;
  float2 p0 = *ppk, p1;
  __hip_bfloat162 g0 = *pg, g1;
  float B0[16], C0[16], B1[16], C1[16];
#pragma unroll
  for (int jj = 0; jj < 4; jj++) {
    ((float4*)B0)[jj] = ((const float4*)(pBC + 32))[jj];
    ((float4*)C0)[jj] = ((const float4*)(pBC + 48))[jj];
  }
  for (int t = 0; t < LC_; t += 2) {
    ppk += DIN_; pBC += 64; pg += DIN_;
    p1 = *ppk; g1 = *pg;
#pragma unroll
    for (int jj = 0; jj < 4; jj++) {
      ((float4*)B1)[jj] = ((const float4*)(pBC + 32))[jj];
      ((float4*)C1)[jj] = ((const float4*)(pBC + 48))[jj];
    }
    {
      float pa = 0.f, pb = 0.f, pc = 0.f, pd = 0.f;
#pragma unroll
      for (int j = 0; j < 4; j++) {
        float dA;
        dA = __builtin_amdgcn_exp2f(p0.x * Ad[4 * j + 0]);
        h[4 * j + 0] = fmaf(dA, h[4 * j + 0], p0.y * B0[4 * j + 0]);
        pa = fmaf(h[4 * j + 0], C0[4 * j + 0], pa);
        dA = __builtin_amdgcn_exp2f(p0.x * Ad[4 * j + 1]);
        h[4 * j + 1] = fmaf(dA, h[4 * j + 1], p0.y * B0[4 * j + 1]);
        pb = fmaf(h[4 * j + 1], C0[4 * j + 1], pb);
        dA = __builtin_amdgcn_exp2f(p0.x * Ad[4 * j + 2]);
        h[4 * j + 2] = fmaf(dA, h[4 * j + 2], p0.y * B0[4 * j + 2]);
        pc = fmaf(h[4 * j + 2], C0[4 * j + 2], pc);
        dA = __builtin_amdgcn_exp2f(p0.x * Ad[4 * j + 3]);
        h[4 * j + 3] = fmaf(dA, h[4 * j + 3], p0.y * B0[4 * j + 3]);
        pd = fmaf(h[4 * j + 3], C0[4 * j + 3], pd);
      }
      float psum = (pa + pb) + (pc + pd);
      float2 gs = __bfloat1622float2(g0);
      *py = __float2bfloat16(fmaf(psum, gs.x, gs.y));
      py += DIN_;
    }
    ppk += DIN_; pBC += 64; pg += DIN_;
    p0 = *ppk; g0 = *pg;
#pragma unroll
    for (int jj = 0; jj < 4; jj++) {
      ((float4*)B0)[jj] = ((const float4*)(pBC + 32))[jj];
      ((float4*)C0)[jj] = ((const float4*)(pBC + 48))[jj];
    }
    {
      float pa = 0.f, pb = 0.f, pc = 0.f, pd = 0.f;
#pragma unroll
      for (int j = 0; j < 4; j++) {
        float dA;
        dA = __builtin_amdgcn_exp2f(p1.x * Ad[4 * j + 0]);
        h[4 * j + 0] = fmaf(dA, h[4 * j + 0], p1.y * B1[4 * j + 0]);
        pa = fmaf(h[4 * j + 0], C1[4 * j + 0], pa);
        dA = __builtin_amdgcn_exp2f(p1.x * Ad[4 * j + 1]);
        h[4 * j + 1] = fmaf(dA, h[4 * j + 1], p1.y * B1[4 * j + 1]);
        pb = fmaf(h[4 * j + 1], C1[4 * j + 1], pb);
        dA = __builtin_amdgcn_exp2f(p1.x * Ad[4 * j + 2]);
        h[4 * j + 2] = fmaf(dA, h[4 * j + 2], p1.y * B1[4 * j + 2]);
        pc = fmaf(h[4 * j + 2], C1[4 * j + 2], pc);
        dA = __builtin_amdgcn_exp2f(p1.x * Ad[4 * j + 3]);
        h[4 * j + 3] = fmaf(dA, h[4 * j + 3], p1.y * B1[4 * j + 3]);
        pd = fmaf(h[4 * j + 3], C1[4 * j + 3], pd);
      }
      float psum = (pa + pb) + (pc + pd);
      float2 gs = __bfloat1622float2(g1);
      *py = __float2bfloat16(fmaf(psum, gs.x, gs.y));
      py += DIN_;
    }
  }
}

extern "C" void kernel_launch(void* const* d_in, const int* in_sizes, int n_in,
                              void* d_out, int out_size, void* d_ws, size_t ws_size,
                              hipStream_t stream) {
  const float* x     = (const float*)d_in[0];
  const float* ln1w  = (const float*)d_in[1];
  const float* ln1b  = (const float*)d_in[2];
  const float* W_in  = (const float*)d_in[3];
  const float* convw = (const float*)d_in[4];
  const float* convb = (const float*)d_in[5];
  const float* W_x   = (const float*)d_in[6];
  const float* W_dt  = (const float*)d_in[7];
  const float* b_dt  = (const float*)d_in[8];
  const float* A_log = (const float*)d_in[9];
  const float* Dskip = (const float*)d_in[10];
  const float* W_out = (const float*)d_in[11];
  const float* ln2w  = (const float*)d_in[12];
  const float* ln2b  = (const float*)d_in[13];
  float* out = (float*)d_out;

  // Workspace layout, 141.1 MiB total (<= 146 MiB proven in round 1). f32-unit offsets:
  constexpr size_t M1 = 1024 * 1024;
  float* wsf = (float*)d_ws;
  float* pk            = wsf;                                  // [0,16M)   (dt,dt*xv) float2
  __hip_bfloat162* PKG = (__hip_bfloat162*)(wsf + 16 * M1);    // [16M,24M) (g, xv*D*g) bf16x2
  __hip_bfloat16* xcb  = (__hip_bfloat16*)(wsf + 24 * M1);     // [24M,28M) conv xv -> y
  float* dbl           = wsf + 28 * M1;                        // [28M,28.5M) dt_r|B|C
  float* Pb            = dbl + (size_t)BL_ * 64;               // 2M
  float* Sb            = Pb + 2 * M1;                          // 2M
  float* h0            = Sb + 2 * M1;                          // 2M
  __hip_bfloat16* wt_in  = (__hip_bfloat16*)(h0 + 2 * M1);     // 2048x512 bf16
  __hip_bfloat16* wt_x   = wt_in + 2048 * 512;                 // 64x1024 bf16
  __hip_bfloat16* wt_out = wt_x + 64 * 1024;                   // 512x1024 bf16
  // overlays (liveness-disjoint):
  __hip_bfloat16* XP   = (__hip_bfloat16*)wsf;                 // [0,4M) xp bf16, dead after conv
  __hip_bfloat16* Gb   = (__hip_bfloat16*)(wsf + 4 * M1);      // [4M,8M) g bf16, dead after conv
  __hip_bfloat16* xnb  = (__hip_bfloat16*)Pb;                  // LN1 out, dead before scan1
  float* ymid          = wsf;                                  // [0,4M), after pk is dead

  // weight transposes + dbl zero (independent of LN)
  transpose_cast_k<<<dim3(2048 / 32, 512 / 32), 256, 0, stream>>>(W_in, wt_in, 512, 2048);
  transpose_cast_k<<<dim3(64 / 32, 1024 / 32), 256, 0, stream>>>(W_x, wt_x, 1024, 64);
  transpose_cast_k<<<dim3(512 / 32, 1024 / 32), 256, 0, stream>>>(W_out, wt_out, 1024, 512);
  zero_k<<<(BL_ * 64) / 1024, 256, 0, stream>>>((float4*)dbl);
  // 1. LN1 -> bf16
  ln_k<false, __hip_bfloat16><<<BL_, 256, 0, stream>>>(x, nullptr, ln1w, ln1b, xnb);
  // 2. in-proj GEMM (8192x2048x512): xp half -> XP bf16; z half -> g=silu(z) bf16
  gemm_mfma_k<1><<<dim3(2048 / 128, BL_ / 128), 256, 0, stream>>>(
      xnb, wt_in, nullptr, XP, Gb, BL_, 2048, 512);
  // 3. causal conv + silu -> xcb bf16; pack gate pair PKG
  conv_silu_k<<<(BL_ * 512) / 256, 256, 0, stream>>>(XP, Gb, convw, convb, Dskip, xcb, PKG);
  // 4. dbl += xcb @ wt_x^T  (8192 x 64 x 1024) MFMA split-K=4
  gemm_mfma_n64_k<<<dim3(4, BL_ / 128), 256, 0, stream>>>(xcb, wt_x, dbl, BL_, DIN_);
  // 5. dt GEMM + softplus + pk=(dt, dt*xv) epilogue  (XP/Gb dead -> pk overlay OK)
  gemm_dt_k<<<dim3(DIN_ / 64, BL_ / 64), 256, 0, stream>>>(dbl, W_dt, b_dt, xcb, pk);
  // 6. chunked selective scan
  scan1_k<<<B_ * NC_ * (DIN_ / 256), 256, 0, stream>>>(
      (const float2*)pk, dbl, A_log, Pb, Sb);
  comb_k<<<(B_ * DIN_ * NST) / 256, 256, 0, stream>>>(Pb, Sb, h0);
  scan3_k<<<B_ * NC_ * (DIN_ / 256), 256, 0, stream>>>(
      (const float2*)pk, dbl, A_log, PKG, h0, xcb);
  // 7. ymid = y @ wt_out^T  (8192 x 512 x 1024) MFMA (pk dead -> ymid overlay OK)
  gemm_mfma_k<0><<<dim3(512 / 128, BL_ / 128), 256, 0, stream>>>(
      xcb, wt_out, ymid, nullptr, nullptr, BL_, 512, 1024);
  // 8. out = LN2(x + ymid)
  ln_k<true, float><<<BL_, 256, 0, stream>>>(x, ymid, ln2w, ln2b, out);
}

// Round 6
// 312.913 us; speedup vs baseline: 4.5363x; 1.0160x over previous
//
#include <hip/hip_runtime.h>
#include <hip/hip_bf16.h>
#include <math.h>

// Problem constants (match reference)
constexpr int B_   = 8;
constexpr int L_   = 1024;
constexpr int D_   = 512;
constexpr int DIN_ = 1024;   // EXPAND * D
constexpr int NST  = 16;     // DSTATE
constexpr int DTR  = 32;     // DTRANK
constexpr int BL_  = B_ * L_;
constexpr int NC_  = 32;     // time chunks for parallel scan
constexpr int LC_  = L_ / NC_;  // 32 steps per chunk
#define EPSV 1e-5f
constexpr float LOG2E_ = 1.4426950408889634f;

typedef __attribute__((ext_vector_type(8))) short short8;   // 8 bf16 = 4 VGPRs (MFMA A/B frag)
typedef __attribute__((ext_vector_type(4))) float f32x4;    // MFMA C/D frag

__device__ __forceinline__ float fsig(float x) {   // fast sigmoid (exp2+rcp)
  return __builtin_amdgcn_rcpf(1.f + __builtin_amdgcn_exp2f(-x * LOG2E_));
}
__device__ __forceinline__ float softplusf_(float x) { return fmaxf(x, 0.f) + log1pf(expf(-fabsf(x))); }

// async global->LDS, 16B per lane. LDS dest = wave-uniform base + lane*16.
__device__ __forceinline__ void gld16(const void* g, void* l) {
  __builtin_amdgcn_global_load_lds((const __attribute__((address_space(1))) void*)g,
                                   (__attribute__((address_space(3))) void*)l, 16, 0, 0);
}

// ---------------- LayerNorm over D_=512. block=256, 2 cols/thread. ----------------
template <bool RES, typename TO>
__global__ __launch_bounds__(256) void ln_k(const float* __restrict__ x,
                                            const float* __restrict__ res,
                                            const float* __restrict__ w,
                                            const float* __restrict__ b,
                                            TO* __restrict__ out) {
  int row = blockIdx.x;
  int tid = threadIdx.x;
  const float* xr = x + (size_t)row * D_;
  float v0 = xr[tid], v1 = xr[tid + 256];
  if (RES) {
    const float* rr = res + (size_t)row * D_;
    v0 += rr[tid];
    v1 += rr[tid + 256];
  }
  float s = v0 + v1, ss = v0 * v0 + v1 * v1;
  __shared__ float r1[256], r2[256];
  r1[tid] = s; r2[tid] = ss;
  __syncthreads();
  for (int off = 128; off > 0; off >>= 1) {
    if (tid < off) { r1[tid] += r1[tid + off]; r2[tid] += r2[tid + off]; }
    __syncthreads();
  }
  float mean = r1[0] * (1.f / D_);
  float var  = r2[0] * (1.f / D_) - mean * mean;
  float rs   = rsqrtf(var + EPSV);
  float o0 = (v0 - mean) * rs * w[tid] + b[tid];
  float o1 = (v1 - mean) * rs * w[tid + 256] + b[tid + 256];
  TO* orow = out + (size_t)row * D_;
  if constexpr (sizeof(TO) == 2) {
    orow[tid]       = __float2bfloat16(o0);
    orow[tid + 256] = __float2bfloat16(o1);
  } else {
    orow[tid]       = o0;
    orow[tid + 256] = o1;
  }
}

// ---------------- prep: 3 weight transpose-casts + dbl zero, one launch ----------------
// W (K x N f32) -> Wt (N x K bf16), 32x32 tiles. Block-uniform branch on blockIdx.
__global__ __launch_bounds__(256) void prep_k(const float* __restrict__ W_in,
                                              const float* __restrict__ W_x,
                                              const float* __restrict__ W_out,
                                              __hip_bfloat16* __restrict__ wt_in,
                                              __hip_bfloat16* __restrict__ wt_x,
                                              __hip_bfloat16* __restrict__ wt_out,
                                              float4* __restrict__ dblz) {
  int bx = blockIdx.x;
  const float* W; __hip_bfloat16* Wt; int K, N, tn, tk;
  if (bx < 1024)      { W = W_in;  Wt = wt_in;  K = 512;  N = 2048; int i = bx;        tn = i & 63; tk = i >> 6; }
  else if (bx < 1088) { W = W_x;   Wt = wt_x;   K = 1024; N = 64;   int i = bx - 1024; tn = i & 1;  tk = i >> 1; }
  else if (bx < 1600) { W = W_out; Wt = wt_out; K = 1024; N = 512;  int i = bx - 1088; tn = i & 15; tk = i >> 4; }
  else {  // zero dbl: 512 blocks x 256 thr x 16B = 2 MiB
    int i = bx - 1600;
    dblz[(size_t)i * 256 + threadIdx.x] = float4{0.f, 0.f, 0.f, 0.f};
    return;
  }
  __shared__ float t[32][33];
  int c = threadIdx.x & 31, r8 = threadIdx.x >> 5;
  int n0 = tn * 32, k0 = tk * 32;
#pragma unroll
  for (int rr = 0; rr < 4; rr++)
    t[r8 + rr * 8][c] = W[(size_t)(k0 + r8 + rr * 8) * N + n0 + c];
  __syncthreads();
#pragma unroll
  for (int rr = 0; rr < 4; rr++)
    Wt[(size_t)(n0 + r8 + rr * 8) * K + k0 + c] = __float2bfloat16(t[c][r8 + rr * 8]);
}

// ---------------- bf16 MFMA GEMM: 128x128 tile, BK=32, 4 waves. ------------
// EPI=0: plain f32 store to C. EPI=1 (in-proj, N=2048): xp half -> bf16 XP;
// z half -> g = z*sigmoid(z) bf16 into Gb.
template <int EPI>
__global__ __launch_bounds__(256) void gemm_mfma_k(const __hip_bfloat16* __restrict__ A,
                                                   const __hip_bfloat16* __restrict__ Bt,
                                                   float* __restrict__ C,
                                                   __hip_bfloat16* __restrict__ XP,
                                                   __hip_bfloat16* __restrict__ Gb,
                                                   int M, int N, int K) {
  __shared__ __align__(16) __hip_bfloat16 As[128 * 32];
  __shared__ __align__(16) __hip_bfloat16 Bs[128 * 32];
  int tid = threadIdx.x, w = tid >> 6, l = tid & 63;
  int m0 = blockIdx.y * 128, n0 = blockIdx.x * 128;
  int wm = (w >> 1) * 64, wn = (w & 1) * 64;
  int m16 = l & 15, q = l >> 4;
  int lr = l >> 2, lc = (l & 3) * 8;
  f32x4 acc[4][4] = {};
  for (int k0 = 0; k0 < K; k0 += 32) {
#pragma unroll
    for (int p = 0; p < 2; p++) {
      int rg = p * 4 + w;
      gld16(A  + (size_t)(m0 + rg * 16 + lr) * K + k0 + lc, As + rg * 512);
      gld16(Bt + (size_t)(n0 + rg * 16 + lr) * K + k0 + lc, Bs + rg * 512);
    }
    __syncthreads();
    short8 av[4], bv[4];
#pragma unroll
    for (int i = 0; i < 4; i++)
      av[i] = *(const short8*)(As + (wm + i * 16 + m16) * 32 + q * 8);
#pragma unroll
    for (int j = 0; j < 4; j++)
      bv[j] = *(const short8*)(Bs + (wn + j * 16 + m16) * 32 + q * 8);
#pragma unroll
    for (int i = 0; i < 4; i++)
#pragma unroll
      for (int j = 0; j < 4; j++)
        acc[i][j] = __builtin_amdgcn_mfma_f32_16x16x32_bf16(av[i], bv[j], acc[i][j], 0, 0, 0);
    __syncthreads();
  }
  // C/D layout: col = lane&15, row = (lane>>4)*4 + r  [m89/m91 verified]
  if (EPI == 0) {
#pragma unroll
    for (int i = 0; i < 4; i++)
#pragma unroll
      for (int j = 0; j < 4; j++)
#pragma unroll
        for (int r = 0; r < 4; r++) {
          int gm = m0 + wm + i * 16 + q * 4 + r;
          int gn = n0 + wn + j * 16 + m16;
          C[(size_t)gm * N + gn] = acc[i][j][r];
        }
  } else {
    bool isz = (n0 >= DIN_);             // uniform per block (128 | 1024)
    int colbase = n0 - (isz ? DIN_ : 0);
#pragma unroll
    for (int i = 0; i < 4; i++)
#pragma unroll
      for (int j = 0; j < 4; j++)
#pragma unroll
        for (int r = 0; r < 4; r++) {
          int gm = m0 + wm + i * 16 + q * 4 + r;
          int cl = colbase + wn + j * 16 + m16;
          float v = acc[i][j][r];
          if (!isz) XP[(size_t)gm * DIN_ + cl] = __float2bfloat16(v);
          else      Gb[(size_t)gm * DIN_ + cl] = __float2bfloat16(v * fsig(v));
        }
  }
}

// ---- N=64 variant with split-K (for xp @ W_x): tile 128x64, grid=(SK, M/128), atomicAdd.
__global__ __launch_bounds__(256) void gemm_mfma_n64_k(const __hip_bfloat16* __restrict__ A,
                                                       const __hip_bfloat16* __restrict__ Bt,
                                                       float* __restrict__ C,
                                                       int M, int K) {
  __shared__ __align__(16) __hip_bfloat16 As[128 * 32];
  __shared__ __align__(16) __hip_bfloat16 Bs[64 * 32];
  int tid = threadIdx.x, w = tid >> 6, l = tid & 63;
  int m0 = blockIdx.y * 128;
  int kper = K / gridDim.x, kbeg = blockIdx.x * kper;
  int m16 = l & 15, q = l >> 4;
  int lr = l >> 2, lc = (l & 3) * 8;
  f32x4 acc[2][4] = {};
  for (int k0 = kbeg; k0 < kbeg + kper; k0 += 32) {
#pragma unroll
    for (int p = 0; p < 2; p++) {
      int rg = p * 4 + w;
      gld16(A + (size_t)(m0 + rg * 16 + lr) * K + k0 + lc, As + rg * 512);
    }
    gld16(Bt + (size_t)(w * 16 + lr) * K + k0 + lc, Bs + w * 512);
    __syncthreads();
    short8 av[2], bv[4];
#pragma unroll
    for (int i = 0; i < 2; i++)
      av[i] = *(const short8*)(As + (w * 32 + i * 16 + m16) * 32 + q * 8);
#pragma unroll
    for (int j = 0; j < 4; j++)
      bv[j] = *(const short8*)(Bs + (j * 16 + m16) * 32 + q * 8);
#pragma unroll
    for (int i = 0; i < 2; i++)
#pragma unroll
      for (int j = 0; j < 4; j++)
        acc[i][j] = __builtin_amdgcn_mfma_f32_16x16x32_bf16(av[i], bv[j], acc[i][j], 0, 0, 0);
    __syncthreads();
  }
#pragma unroll
  for (int i = 0; i < 2; i++)
#pragma unroll
    for (int j = 0; j < 4; j++)
#pragma unroll
      for (int r = 0; r < 4; r++) {
        int gm = m0 + w * 32 + i * 16 + q * 4 + r;
        int gn = j * 16 + m16;
        atomicAdd(&C[(size_t)gm * 64 + gn], acc[i][j][r]);
      }
}

// ---------------- dt GEMM (8192x1024x32, f32) + softplus -> dtb f32 ----------------
__global__ __launch_bounds__(256) void gemm_dt_k(const float* __restrict__ A,   // dbl, lda=64
                                                 const float* __restrict__ Bw,  // W_dt [32][1024]
                                                 const float* __restrict__ bias,
                                                 float* __restrict__ dtb) {
  constexpr int BK = 16, LDP = 68;
  __shared__ float As[BK * LDP];
  __shared__ float Bs[BK * LDP];
  int tid = threadIdx.x;
  int m0 = blockIdx.y * 64, n0 = blockIdx.x * 64;
  int tn = tid & 15, tm = tid >> 4;
  int am = tid >> 2, ak = (tid & 3) * 4;
  int bn = tid & 63, bk = tid >> 6;
  float acc[4][4] = {};
  for (int k0 = 0; k0 < DTR; k0 += BK) {
    float4 av = *(const float4*)(A + (size_t)(m0 + am) * 64 + k0 + ak);
    As[(ak + 0) * LDP + am] = av.x;
    As[(ak + 1) * LDP + am] = av.y;
    As[(ak + 2) * LDP + am] = av.z;
    As[(ak + 3) * LDP + am] = av.w;
#pragma unroll
    for (int i = 0; i < 4; i++)
      Bs[(bk + 4 * i) * LDP + bn] = Bw[(size_t)(k0 + bk + 4 * i) * DIN_ + n0 + bn];
    __syncthreads();
#pragma unroll
    for (int kk = 0; kk < BK; kk++) {
      float4 a4 = *(const float4*)(As + kk * LDP + tm * 4);
      float4 b4 = *(const float4*)(Bs + kk * LDP + tn * 4);
      float a[4] = {a4.x, a4.y, a4.z, a4.w};
      float bb[4] = {b4.x, b4.y, b4.z, b4.w};
#pragma unroll
      for (int i = 0; i < 4; i++)
#pragma unroll
        for (int j = 0; j < 4; j++) acc[i][j] = fmaf(a[i], bb[j], acc[i][j]);
    }
    __syncthreads();
  }
#pragma unroll
  for (int i = 0; i < 4; i++) {
    int gm = m0 + tm * 4 + i;
    int gn = n0 + tn * 4;
    float v[4];
#pragma unroll
    for (int j = 0; j < 4; j++) v[j] = softplusf_(acc[i][j] + bias[gn + j]);
    *(float4*)(dtb + (size_t)gm * DIN_ + gn) = float4{v[0], v[1], v[2], v[3]};
  }
}

// ---------------- Causal depthwise conv (k=4) + bias + SiLU; 2 channels/thread -------
// Also packs gate pair PKG = (g, xv*D*g) bf16x2 per (t,d), consuming g from Gb.
__global__ __launch_bounds__(256) void conv_silu_k(const __hip_bfloat16* __restrict__ XP,
                                                   const __hip_bfloat16* __restrict__ Gb,
                                                   const float* __restrict__ cw,
                                                   const float* __restrict__ cb,
                                                   const float* __restrict__ Dsk,
                                                   __hip_bfloat16* __restrict__ xcb,
                                                   __hip_bfloat162* __restrict__ PKG) {
  int idx = blockIdx.x * 256 + threadIdx.x;  // over BL_*512 channel pairs
  int dp = idx & 511;
  int d  = dp * 2;
  int bl = idx >> 9;
  int t  = bl & (L_ - 1);
  float4 w0 = *(const float4*)(cw + d * 4);
  float4 w1 = *(const float4*)(cw + d * 4 + 4);
  float w0a[4] = {w0.x, w0.y, w0.z, w0.w};
  float w1a[4] = {w1.x, w1.y, w1.z, w1.w};
  float a0 = cb[d], a1 = cb[d + 1];
#pragma unroll
  for (int j = 0; j < 4; j++) {
    int tt = t - 3 + j;
    if (tt >= 0) {
      __hip_bfloat162 xp2 = *(const __hip_bfloat162*)(XP + (size_t)(bl + j - 3) * DIN_ + d);
      float2 xf = __bfloat1622float2(xp2);
      a0 = fmaf(xf.x, w0a[j], a0);
      a1 = fmaf(xf.y, w1a[j], a1);
    }
  }
  float xv0 = a0 * fsig(a0), xv1 = a1 * fsig(a1);
  __hip_bfloat162 xo;
  xo.x = __float2bfloat16(xv0); xo.y = __float2bfloat16(xv1);
  *(__hip_bfloat162*)(xcb + (size_t)bl * DIN_ + d) = xo;
  __hip_bfloat162 g2 = *(const __hip_bfloat162*)(Gb + (size_t)bl * DIN_ + d);
  float2 gf = __bfloat1622float2(g2);
  __hip_bfloat162 o0, o1;
  o0.x = g2.x; o0.y = __float2bfloat16(xv0 * Dsk[d] * gf.x);
  o1.x = g2.y; o1.y = __float2bfloat16(xv1 * Dsk[d + 1] * gf.y);
  PKG[(size_t)bl * DIN_ + d]     = o0;
  PKG[(size_t)bl * DIN_ + d + 1] = o1;
}

// ---------------- Chunked selective scan: ONE LANE = ONE d, 16 states in regs ----------
// dtx = dt * xv recomputed from dtb f32 + xcb bf16 (no float2 pk buffer).
// B/C block-uniform -> scalar loads. grid = B*NC*(DIN/256) = 1024 blocks (4/CU).
// Double-buffered prefetch; 1-row overreach at chunk end stays inside d_ws (discarded).
__global__ __launch_bounds__(256) void scan1_k(const float* __restrict__ dtb,
                                               const __hip_bfloat16* __restrict__ xcb,
                                               const float* __restrict__ dbl,
                                               const float* __restrict__ A_log,
                                               float* __restrict__ Pb,
                                               float* __restrict__ Sb) {
  int tid = threadIdx.x, bx = blockIdx.x;
  int d = (bx & 3) * 256 + tid;
  int c = (bx >> 2) & (NC_ - 1);
  int b = bx >> 7;
  float Ad[16];
#pragma unroll
  for (int jj = 0; jj < 4; jj++) {
    float4 a4 = *(const float4*)(A_log + d * NST + jj * 4);
    Ad[jj * 4 + 0] = -expf(a4.x) * LOG2E_;
    Ad[jj * 4 + 1] = -expf(a4.y) * LOG2E_;
    Ad[jj * 4 + 2] = -expf(a4.z) * LOG2E_;
    Ad[jj * 4 + 3] = -expf(a4.w) * LOG2E_;
  }
  size_t row0 = (size_t)b * L_ + (size_t)c * LC_;
  const float* pdt = dtb + row0 * DIN_ + d;
  const __hip_bfloat16* pxv = xcb + row0 * DIN_ + d;
  const float* pB = dbl + row0 * 64 + 32;
  float t0 = *pdt, t1;
  float x0 = __bfloat162float(*pxv), x1;
  float B0[16], B1[16];
#pragma unroll
  for (int jj = 0; jj < 4; jj++) ((float4*)B0)[jj] = ((const float4*)pB)[jj];
  float S[16] = {};
  float Ts = 0.f;
  for (int t = 0; t < LC_; t += 2) {
    pdt += DIN_; pxv += DIN_; pB += 64;
    t1 = *pdt; x1 = __bfloat162float(*pxv);
#pragma unroll
    for (int jj = 0; jj < 4; jj++) ((float4*)B1)[jj] = ((const float4*)pB)[jj];
    {
      float dtx = t0 * x0;
      Ts += t0;
#pragma unroll
      for (int j = 0; j < 16; j++) {
        float dA = __builtin_amdgcn_exp2f(t0 * Ad[j]);
        S[j] = fmaf(dA, S[j], dtx * B0[j]);
      }
    }
    pdt += DIN_; pxv += DIN_; pB += 64;
    t0 = *pdt; x0 = __bfloat162float(*pxv);
#pragma unroll
    for (int jj = 0; jj < 4; jj++) ((float4*)B0)[jj] = ((const float4*)pB)[jj];
    {
      float dtx = t1 * x1;
      Ts += t1;
#pragma unroll
      for (int j = 0; j < 16; j++) {
        float dA = __builtin_amdgcn_exp2f(t1 * Ad[j]);
        S[j] = fmaf(dA, S[j], dtx * B1[j]);
      }
    }
  }
  size_t oidx = ((size_t)(b * NC_ + c) * DIN_ + d) * NST;
#pragma unroll
  for (int jj = 0; jj < 4; jj++) {
    float4 Pv = {__builtin_amdgcn_exp2f(Ts * Ad[jj * 4 + 0]),
                 __builtin_amdgcn_exp2f(Ts * Ad[jj * 4 + 1]),
                 __builtin_amdgcn_exp2f(Ts * Ad[jj * 4 + 2]),
                 __builtin_amdgcn_exp2f(Ts * Ad[jj * 4 + 3])};
    *(float4*)(Pb + oidx + jj * 4) = Pv;
    *(float4*)(Sb + oidx + jj * 4) = float4{S[jj * 4 + 0], S[jj * 4 + 1],
                                            S[jj * 4 + 2], S[jj * 4 + 3]};
  }
}

// Pass 2: sequential combine over NC_ chunks -> per-chunk initial state h0.
__global__ __launch_bounds__(256) void comb_k(const float* __restrict__ Pb,
                                              const float* __restrict__ Sb,
                                              float* __restrict__ h0) {
  int gid = blockIdx.x * 256 + threadIdx.x;  // over B_*DIN_*NST
  int b   = gid >> 14;
  int rem = gid & (DIN_ * NST - 1);
  float h = 0.f;
#pragma unroll
  for (int c = 0; c < NC_; ++c) {
    size_t idx = (size_t)(b * NC_ + c) * DIN_ * NST + rem;
    h0[idx] = h;
    h = fmaf(Pb[idx], h, Sb[idx]);
  }
}

// Pass 3: re-run chunk from h0; y = psum*g + skipg (PKG precomputed); bf16 y IN PLACE
// over xcb. Safe: lane-private column d; prefetch of row t+1 issued before store to row t.
__global__ __launch_bounds__(256) void scan3_k(const float* __restrict__ dtb,
                                               const float* __restrict__ dbl,
                                               const float* __restrict__ A_log,
                                               const __hip_bfloat162* __restrict__ PKG,
                                               const float* __restrict__ h0,
                                               __hip_bfloat16* __restrict__ xcb) {
  int tid = threadIdx.x, bx = blockIdx.x;
  int d = (bx & 3) * 256 + tid;
  int c = (bx >> 2) & (NC_ - 1);
  int b = bx >> 7;
  float Ad[16];
#pragma unroll
  for (int jj = 0; jj < 4; jj++) {
    float4 a4 = *(const float4*)(A_log + d * NST + jj * 4);
    Ad[jj * 4 + 0] = -expf(a4.x) * LOG2E_;
    Ad[jj * 4 + 1] = -expf(a4.y) * LOG2E_;
    Ad[jj * 4 + 2] = -expf(a4.z) * LOG2E_;
    Ad[jj * 4 + 3] = -expf(a4.w) * LOG2E_;
  }
  size_t oidx = ((size_t)(b * NC_ + c) * DIN_ + d) * NST;
  float h[16];
#pragma unroll
  for (int jj = 0; jj < 4; jj++) ((float4*)h)[jj] = *(const float4*)(h0 + oidx + jj * 4);
  size_t row0 = (size_t)b * L_ + (size_t)c * LC_;
  const float* pdt = dtb + row0 * DIN_ + d;
  const __hip_bfloat16* pxv = xcb + row0 * DIN_ + d;
  const float* pBC = dbl + row0 * 64;
  const __hip_bfloat162* pg = PKG + row0 * DIN_ + d;
  __hip_bfloat16* py = xcb + row0 * DIN_ + d;
  float t0 = *pdt, t1;
  float x0 = __bfloat162float(*pxv), x1;
  __hip_bfloat162 g0 = *pg, g1;
  float B0[16], C0[16], B1[16], C1[16];
#pragma unroll
  for (int jj = 0; jj < 4; jj++) {
    ((float4*)B0)[jj] = ((const float4*)(pBC + 32))[jj];
    ((float4*)C0)[jj] = ((const float4*)(pBC + 48))[jj];
  }
  for (int t = 0; t < LC_; t += 2) {
    pdt += DIN_; pxv += DIN_; pBC += 64; pg += DIN_;
    t1 = *pdt; x1 = __bfloat162float(*pxv); g1 = *pg;
#pragma unroll
    for (int jj = 0; jj < 4; jj++) {
      ((float4*)B1)[jj] = ((const float4*)(pBC + 32))[jj];
      ((float4*)C1)[jj] = ((const float4*)(pBC + 48))[jj];
    }
    {
      float dtx = t0 * x0;
      float pa = 0.f, pb = 0.f, pc = 0.f, pd = 0.f;
#pragma unroll
      for (int j = 0; j < 4; j++) {
        float dA;
        dA = __builtin_amdgcn_exp2f(t0 * Ad[4 * j + 0]);
        h[4 * j + 0] = fmaf(dA, h[4 * j + 0], dtx * B0[4 * j + 0]);
        pa = fmaf(h[4 * j + 0], C0[4 * j + 0], pa);
        dA = __builtin_amdgcn_exp2f(t0 * Ad[4 * j + 1]);
        h[4 * j + 1] = fmaf(dA, h[4 * j + 1], dtx * B0[4 * j + 1]);
        pb = fmaf(h[4 * j + 1], C0[4 * j + 1], pb);
        dA = __builtin_amdgcn_exp2f(t0 * Ad[4 * j + 2]);
        h[4 * j + 2] = fmaf(dA, h[4 * j + 2], dtx * B0[4 * j + 2]);
        pc = fmaf(h[4 * j + 2], C0[4 * j + 2], pc);
        dA = __builtin_amdgcn_exp2f(t0 * Ad[4 * j + 3]);
        h[4 * j + 3] = fmaf(dA, h[4 * j + 3], dtx * B0[4 * j + 3]);
        pd = fmaf(h[4 * j + 3], C0[4 * j + 3], pd);
      }
      float psum = (pa + pb) + (pc + pd);
      float2 gs = __bfloat1622float2(g0);
      *py = __float2bfloat16(fmaf(psum, gs.x, gs.y));
      py += DIN_;
    }
    pdt += DIN_; pxv += DIN_; pBC += 64; pg += DIN_;
    t0 = *pdt; x0 = __bfloat162float(*pxv); g0 = *pg;
#pragma unroll
    for (int jj = 0; jj < 4; jj++) {
      ((float4*)B0)[jj] = ((const float4*)(pBC + 32))[jj];
      ((float4*)C0)[jj] = ((const float4*)(pBC + 48))[jj];
    }
    {
      float dtx = t1 * x1;
      float pa = 0.f, pb = 0.f, pc = 0.f, pd = 0.f;
#pragma unroll
      for (int j = 0; j < 4; j++) {
        float dA;
        dA = __builtin_amdgcn_exp2f(t1 * Ad[4 * j + 0]);
        h[4 * j + 0] = fmaf(dA, h[4 * j + 0], dtx * B1[4 * j + 0]);
        pa = fmaf(h[4 * j + 0], C1[4 * j + 0], pa);
        dA = __builtin_amdgcn_exp2f(t1 * Ad[4 * j + 1]);
        h[4 * j + 1] = fmaf(dA, h[4 * j + 1], dtx * B1[4 * j + 1]);
        pb = fmaf(h[4 * j + 1], C1[4 * j + 1], pb);
        dA = __builtin_amdgcn_exp2f(t1 * Ad[4 * j + 2]);
        h[4 * j + 2] = fmaf(dA, h[4 * j + 2], dtx * B1[4 * j + 2]);
        pc = fmaf(h[4 * j + 2], C1[4 * j + 2], pc);
        dA = __builtin_amdgcn_exp2f(t1 * Ad[4 * j + 3]);
        h[4 * j + 3] = fmaf(dA, h[4 * j + 3], dtx * B1[4 * j + 3]);
        pd = fmaf(h[4 * j + 3], C1[4 * j + 3], pd);
      }
      float psum = (pa + pb) + (pc + pd);
      float2 gs = __bfloat1622float2(g1);
      *py = __float2bfloat16(fmaf(psum, gs.x, gs.y));
      py += DIN_;
    }
  }
}

extern "C" void kernel_launch(void* const* d_in, const int* in_sizes, int n_in,
                              void* d_out, int out_size, void* d_ws, size_t ws_size,
                              hipStream_t stream) {
  const float* x     = (const float*)d_in[0];
  const float* ln1w  = (const float*)d_in[1];
  const float* ln1b  = (const float*)d_in[2];
  const float* W_in  = (const float*)d_in[3];
  const float* convw = (const float*)d_in[4];
  const float* convb = (const float*)d_in[5];
  const float* W_x   = (const float*)d_in[6];
  const float* W_dt  = (const float*)d_in[7];
  const float* b_dt  = (const float*)d_in[8];
  const float* A_log = (const float*)d_in[9];
  const float* Dskip = (const float*)d_in[10];
  const float* W_out = (const float*)d_in[11];
  const float* ln2w  = (const float*)d_in[12];
  const float* ln2b  = (const float*)d_in[13];
  float* out = (float*)d_out;

  // Workspace layout, ~133 MiB (<= 141 MiB proven in round 4). f32-unit offsets:
  constexpr size_t M1 = 1024 * 1024;
  float* wsf = (float*)d_ws;
  float* dtb           = wsf;                                  // [0,8M)    softplus dt f32
  __hip_bfloat162* PKG = (__hip_bfloat162*)(wsf + 8 * M1);     // [8M,16M)  (g, xv*D*g) bf16x2
  __hip_bfloat16* xcb  = (__hip_bfloat16*)(wsf + 16 * M1);     // [16M,20M) conv xv -> y (in place)
  float* dbl           = wsf + 20 * M1;                        // [20M,20.5M) dt_r|B|C
  float* Pb            = dbl + (size_t)BL_ * 64;               // 4M
  float* Sb            = Pb + 4 * M1;                          // 4M
  float* h0            = Sb + 4 * M1;                          // 4M
  __hip_bfloat16* wt_in  = (__hip_bfloat16*)(h0 + 4 * M1);     // 2048x512 bf16
  __hip_bfloat16* wt_x   = wt_in + 2048 * 512;                 // 64x1024 bf16
  __hip_bfloat16* wt_out = wt_x + 64 * 1024;                   // 512x1024 bf16
  // overlays (liveness-disjoint):
  __hip_bfloat16* XP   = (__hip_bfloat16*)wsf;                 // [0,4M) xp bf16, dead before gemm_dt
  __hip_bfloat16* Gb   = (__hip_bfloat16*)(wsf + 4 * M1);      // [4M,8M) g bf16, dead before gemm_dt
  __hip_bfloat16* xnb  = (__hip_bfloat16*)Pb;                  // LN1 out, dead before scan1
  float* ymid          = wsf;                                  // [0,4M), after dtb is dead (post-scan3)

  // 0. prep: 3 weight transpose-casts + dbl zero (one launch)
  prep_k<<<2112, 256, 0, stream>>>(W_in, W_x, W_out, wt_in, wt_x, wt_out, (float4*)dbl);
  // 1. LN1 -> bf16
  ln_k<false, __hip_bfloat16><<<BL_, 256, 0, stream>>>(x, nullptr, ln1w, ln1b, xnb);
  // 2. in-proj GEMM (8192x2048x512): xp half -> XP bf16; z half -> g=silu(z) bf16
  gemm_mfma_k<1><<<dim3(2048 / 128, BL_ / 128), 256, 0, stream>>>(
      xnb, wt_in, nullptr, XP, Gb, BL_, 2048, 512);
  // 3. causal conv + silu -> xcb bf16; pack gate pair PKG
  conv_silu_k<<<(BL_ * 512) / 256, 256, 0, stream>>>(XP, Gb, convw, convb, Dskip, xcb, PKG);
  // 4. dbl += xcb @ wt_x^T  (8192 x 64 x 1024) MFMA split-K=4
  gemm_mfma_n64_k<<<dim3(4, BL_ / 128), 256, 0, stream>>>(xcb, wt_x, dbl, BL_, DIN_);
  // 5. dt GEMM + softplus -> dtb f32 (XP/Gb dead -> overlay OK)
  gemm_dt_k<<<dim3(DIN_ / 64, BL_ / 64), 256, 0, stream>>>(dbl, W_dt, b_dt, dtb);
  // 6. chunked selective scan (NC=32 -> 1024 blocks)
  scan1_k<<<B_ * NC_ * (DIN_ / 256), 256, 0, stream>>>(dtb, xcb, dbl, A_log, Pb, Sb);
  comb_k<<<(B_ * DIN_ * NST) / 256, 256, 0, stream>>>(Pb, Sb, h0);
  scan3_k<<<B_ * NC_ * (DIN_ / 256), 256, 0, stream>>>(dtb, dbl, A_log, PKG, h0, xcb);
  // 7. ymid = y @ wt_out^T  (8192 x 512 x 1024) MFMA (dtb dead -> ymid overlay OK)
  gemm_mfma_k<0><<<dim3(512 / 128, BL_ / 128), 256, 0, stream>>>(
      xcb, wt_out, ymid, nullptr, nullptr, BL_, 512, 1024);
  // 8. out = LN2(x + ymid)
  ln_k<true, float><<<BL_, 256, 0, stream>>>(x, ymid, ln2w, ln2b, out);
}